// Round 3
// baseline (7750.258 us; speedup 1.0000x reference)
//
#include <hip/hip_runtime.h>
#include <hip/hip_bf16.h>

#define N_    20000
#define S_    20
#define NC_   400000
#define EC_   2000000
#define EB_   200000
#define NIN_  64
#define HOP_  16
#define D_    80
#define NOUT_ 64
#define NB_   1563   // ceil(NC/256)

// ---------------- bf16 pack/unpack (pair layout: lo=feat 2p, hi=feat 2p+1) ----------------
__device__ __forceinline__ float2 bf2f(unsigned u) {
    float2 r;
    r.x = __uint_as_float(u << 16);
    r.y = __uint_as_float(u & 0xffff0000u);
    return r;
}
__device__ __forceinline__ unsigned f2bf_rne(float f) {
    unsigned u = __float_as_uint(f);
    return (u + 0x7fffu + ((u >> 16) & 1u)) >> 16;
}
__device__ __forceinline__ unsigned pack2(float a, float b) {
    return f2bf_rne(a) | (f2bf_rne(b) << 16);
}

// ---------------- scan utility (block of 256 = 4 waves) ----------------
__device__ __forceinline__ int blockExclScan(int v, int tid, int* lds, int* total) {
    int lane = tid & 63;
    int w = tid >> 6;
    int x = v;
    #pragma unroll
    for (int off = 1; off < 64; off <<= 1) {
        int y = __shfl_up(x, off, 64);
        if (lane >= off) x += y;
    }
    if (lane == 63) lds[w] = x;
    __syncthreads();
    if (tid == 0) {
        int acc = 0;
        #pragma unroll
        for (int i = 0; i < 4; i++) { int t = lds[i]; lds[4 + i] = acc; acc += t; }
        lds[8] = acc;
    }
    __syncthreads();
    int res = x - v + lds[4 + w];
    *total = lds[8];
    return res;
}

// ---------------- CSR build ----------------
__global__ __launch_bounds__(256) void k_degree(const int* __restrict__ eidx, int* __restrict__ deg) {
    int e = blockIdx.x * 256 + threadIdx.x;
    if (e >= EC_) return;
    atomicAdd(&deg[eidx[EC_ + e]], 1);
}

__global__ __launch_bounds__(256) void k_bsum(const int* __restrict__ deg, int* __restrict__ bsums) {
    __shared__ int lds[9];
    int i = blockIdx.x * 256 + threadIdx.x;
    int v = (i < NC_) ? deg[i] : 0;
    int tot;
    blockExclScan(v, threadIdx.x, lds, &tot);
    if (threadIdx.x == 0) bsums[blockIdx.x] = tot;
}

__global__ __launch_bounds__(256) void k_scan_bsums(int* __restrict__ bsums) {
    __shared__ int lds[9];
    int carry = 0;
    for (int base = 0; base < NB_; base += 256) {
        int i = base + threadIdx.x;
        int v = (i < NB_) ? bsums[i] : 0;
        int tot;
        int ex = blockExclScan(v, threadIdx.x, lds, &tot);
        if (i < NB_) bsums[i] = ex + carry;
        carry += tot;
        __syncthreads();
    }
}

__global__ __launch_bounds__(256) void k_scan_apply(
    int* __restrict__ cursor, int* __restrict__ start, const int* __restrict__ bsums)
{
    __shared__ int lds[9];
    int i = blockIdx.x * 256 + threadIdx.x;
    int v = (i < NC_) ? cursor[i] : 0;
    int tot;
    int ex = blockExclScan(v, threadIdx.x, lds, &tot);
    if (i < NC_) {
        int s = ex + bsums[blockIdx.x];
        start[i] = s;
        cursor[i] = s;
    }
    if (blockIdx.x == 0 && threadIdx.x == 0) start[NC_] = EC_;
}

__global__ __launch_bounds__(256) void k_fill(
    const int* __restrict__ eidx, const int* __restrict__ emap,
    int* __restrict__ cursor, int2* __restrict__ e2)
{
    int e = blockIdx.x * 256 + threadIdx.x;
    if (e >= EC_) return;
    int src = eidx[e];
    int dst = eidx[EC_ + e];
    int pos = atomicAdd(&cursor[dst], 1);
    e2[pos] = make_int2(src, emap[e]);
}

__global__ __launch_bounds__(256) void k_hist(const int* __restrict__ mapper, int* __restrict__ cntm) {
    int i = blockIdx.x * 256 + threadIdx.x;
    if (i >= NC_) return;
    atomicAdd(&cntm[mapper[i]], 1);
}

// ---------------- h0 = concat(x[mapper], hop_table[hop+1]) as bf16 pairs ----------------
__global__ __launch_bounds__(256) void k_build_h0(
    unsigned* __restrict__ h0, const float* __restrict__ x, const float* __restrict__ ht,
    const int* __restrict__ mapper, const int* __restrict__ hop)
{
    int idx = blockIdx.x * 256 + threadIdx.x;   // NC*40 pair-slots
    if (idx >= NC_ * 40) return;
    int node = idx / 40, t = idx - node * 40;
    float2 v;
    if (t < 32) v = *(const float2*)(x + (size_t)mapper[node] * 64 + 2 * t);
    else        v = *(const float2*)(ht + (size_t)(hop[node] + 1) * 16 + 2 * (t - 32));
    h0[idx] = pack2(v.x, v.y);
}

// ---------------- GINE layer (bf16 h in/out, f32 edge_attr, f32 weights) ----------------
// block = 320 = 8 groups x 40 threads; thread owns features (2t, 2t+1) of its node.
__global__ __launch_bounds__(320) void k_gine(
    const unsigned* __restrict__ hin, unsigned* __restrict__ hout,
    const float* __restrict__ ea, const int* __restrict__ start,
    const int2* __restrict__ e2,
    const float* __restrict__ W, const float* __restrict__ g, const float* __restrict__ b)
{
    __shared__ float sW[D_ * D_];      // 25.6 KB
    __shared__ float sV[8][D_ + 2];
    int tid = threadIdx.x;
    for (int t = tid; t < D_ * D_; t += 320) sW[t] = W[t];
    int grp = tid / 40;
    int t = tid - grp * 40;
    float2 gd = *(const float2*)(g + 2 * t);
    float2 bd = *(const float2*)(b + 2 * t);
    __syncthreads();
    for (int chunk = blockIdx.x; chunk < NC_ / 8; chunk += gridDim.x) {
        int node = chunk * 8 + grp;
        float2 hd = bf2f(hin[(size_t)node * 40 + t]);
        float accx = 0.f, accy = 0.f;
        int e = start[node], s1 = start[node + 1];
        // 4-deep edge batching for memory-level parallelism
        for (; e + 4 <= s1; e += 4) {
            int2 a0 = e2[e], a1 = e2[e + 1], a2 = e2[e + 2], a3 = e2[e + 3];
            unsigned u0 = hin[(size_t)a0.x * 40 + t];
            unsigned u1 = hin[(size_t)a1.x * 40 + t];
            unsigned u2 = hin[(size_t)a2.x * 40 + t];
            unsigned u3 = hin[(size_t)a3.x * 40 + t];
            float2 q0 = *(const float2*)(ea + (size_t)a0.y * D_ + 2 * t);
            float2 q1 = *(const float2*)(ea + (size_t)a1.y * D_ + 2 * t);
            float2 q2 = *(const float2*)(ea + (size_t)a2.y * D_ + 2 * t);
            float2 q3 = *(const float2*)(ea + (size_t)a3.y * D_ + 2 * t);
            float2 f0 = bf2f(u0), f1 = bf2f(u1), f2 = bf2f(u2), f3 = bf2f(u3);
            accx += fmaxf(f0.x + q0.x, 0.f) + fmaxf(f1.x + q1.x, 0.f)
                  + fmaxf(f2.x + q2.x, 0.f) + fmaxf(f3.x + q3.x, 0.f);
            accy += fmaxf(f0.y + q0.y, 0.f) + fmaxf(f1.y + q1.y, 0.f)
                  + fmaxf(f2.y + q2.y, 0.f) + fmaxf(f3.y + q3.y, 0.f);
        }
        for (; e < s1; e++) {
            int2 a = e2[e];
            unsigned u = hin[(size_t)a.x * 40 + t];
            float2 q = *(const float2*)(ea + (size_t)a.y * D_ + 2 * t);
            float2 f = bf2f(u);
            accx += fmaxf(f.x + q.x, 0.f);
            accy += fmaxf(f.y + q.y, 0.f);
        }
        sV[grp][2 * t]     = hd.x + accx;
        sV[grp][2 * t + 1] = hd.y + accy;
        __syncthreads();
        float dx = 0.f, dy = 0.f;
        #pragma unroll
        for (int k = 0; k < D_; k++) {
            float v = sV[grp][k];
            float2 w = *(const float2*)(sW + k * D_ + 2 * t);
            dx += v * w.x;
            dy += v * w.y;
        }
        float ox = fmaxf(gd.x * dx + bd.x, 0.f) + hd.x;
        float oy = fmaxf(gd.y * dy + bd.y, 0.f) + hd.y;
        hout[(size_t)node * 40 + t] = pack2(ox, oy);
        __syncthreads();
    }
}

// ---------------- head: oe + gates + sub/ctx + pooling, one subgraph per block-iter ----------------
// block = 256 = 4 waves; wave w handles nodes n*20 + w*5 .. +4; lane = output dim d.
__global__ __launch_bounds__(256) void k_head(
    const unsigned* __restrict__ h2u, const float* __restrict__ ht,
    const int* __restrict__ hop, const int* __restrict__ mapper,
    const float* __restrict__ oe_w, const float* __restrict__ oe_b,
    const float* __restrict__ sub_w, const float* __restrict__ sub_b,
    const float* __restrict__ sub_g, const float* __restrict__ sub_bt,
    const float* __restrict__ ctx_w, const float* __restrict__ ctx_b,
    const float* __restrict__ ctx_g, const float* __restrict__ ctx_bt,
    const float* __restrict__ gc_w, const float* __restrict__ gc_b,
    const float* __restrict__ gs_w, const float* __restrict__ gs_b,
    const float* __restrict__ gx_w, const float* __restrict__ gx_b,
    float* __restrict__ cent, float* __restrict__ subp, float* __restrict__ ctxp)
{
    __shared__ float sOE[D_ * 64];          // 20 KB
    __shared__ float sSUB[64 * 64];         // 16 KB
    __shared__ float sCTX[64 * 64];         // 16 KB
    __shared__ unsigned short sGC[16 * 64]; // 2 KB (bf16)
    __shared__ unsigned short sGS[16 * 64];
    __shared__ unsigned short sGX[16 * 64];
    __shared__ float sRow[4][D_];           // 1.28 KB
    __shared__ float sC[4][64];             // 1 KB     total ~60.3 KB
    int tid = threadIdx.x;
    for (int i = tid; i < D_ * 64; i += 256) sOE[i] = oe_w[i];
    for (int i = tid; i < 64 * 64; i += 256) { sSUB[i] = sub_w[i]; sCTX[i] = ctx_w[i]; }
    for (int i = tid; i < 16 * 64; i += 256) {
        sGC[i] = (unsigned short)f2bf_rne(gc_w[i]);
        sGS[i] = (unsigned short)f2bf_rne(gs_w[i]);
        sGX[i] = (unsigned short)f2bf_rne(gx_w[i]);
    }
    int d = tid & 63;
    int w = tid >> 6;
    float r_oeb = oe_b[d];
    float r_sb = sub_b[d], r_sg = sub_g[d], r_sbt = sub_bt[d];
    float r_cb = ctx_b[d], r_cg = ctx_g[d], r_cbt = ctx_bt[d];
    float r_gcb = gc_b[d], r_gsb = gs_b[d], r_gxb = gx_b[d];
    __syncthreads();
    for (int n = blockIdx.x; n < N_; n += gridDim.x) {
        float subacc = 0.f;
        #pragma unroll
        for (int i = 0; i < 5; i++) {
            int node = n * 20 + w * 5 + i;
            // stage h2 row into LDS (lanes 0..39 load one bf16-pair each)
            if (d < 40) {
                float2 f = bf2f(h2u[(size_t)node * 40 + d]);
                *(float2*)&sRow[w][2 * d] = f;
            }
            __syncthreads();
            // comb = h2row @ oe_w + oe_b
            float comb = r_oeb;
            #pragma unroll
            for (int k = 0; k < D_; k++) comb += sRow[w][k] * sOE[k * 64 + d];
            // gates from hop embedding
            int hn = hop[node] + 1;
            const float* htr = ht + hn * 16;
            float gs = r_gsb, gx = r_gxb;
            #pragma unroll
            for (int k = 0; k < 16; k++) {
                float hk = htr[k];
                gs += hk * __uint_as_float(((unsigned)sGS[k * 64 + d]) << 16);
                gx += hk * __uint_as_float(((unsigned)sGX[k * 64 + d]) << 16);
            }
            gs = 1.f / (1.f + __expf(-gs));
            gx = 1.f / (1.f + __expf(-gx));
            // sub / ctx transforms (comb broadcast via shfl)
            float sv = r_sb, cv = r_cb;
            #pragma unroll
            for (int k = 0; k < 64; k++) {
                float ck = __shfl(comb, k);
                sv += ck * sSUB[k * 64 + d];
                cv += ck * sCTX[k * 64 + d];
            }
            sv = fmaxf(r_sg * sv + r_sbt, 0.f) * gs;
            cv = fmaxf(r_cg * cv + r_cbt, 0.f) * gx;
            subacc += sv;
            int mm = mapper[node];
            atomicAdd(&ctxp[(size_t)mm * 64 + d], cv);
            if (mm == n) {   // centroid (exactly one per subgraph)
                float gc = r_gcb;
                #pragma unroll
                for (int k = 0; k < 16; k++)
                    gc += htr[k] * __uint_as_float(((unsigned)sGC[k * 64 + d]) << 16);
                gc = 1.f / (1.f + __expf(-gc));
                cent[(size_t)n * 64 + d] = comb * gc;
            }
            __syncthreads();
        }
        // block-reduce sub partial sums (no atomics)
        sC[w][d] = subacc;
        __syncthreads();
        if (w == 0) subp[(size_t)n * 64 + d] = sC[0][d] + sC[1][d] + sC[2][d] + sC[3][d];
        __syncthreads();
    }
}

// ---------------- final: combine pools + out_encoder ----------------
__global__ __launch_bounds__(256) void k_final(
    const float* __restrict__ cent, const float* __restrict__ subp, const float* __restrict__ ctxp,
    const int* __restrict__ cntm,
    const float* __restrict__ fo_w, const float* __restrict__ fo_b,
    const float* __restrict__ fo_g, const float* __restrict__ fo_bt,
    float* __restrict__ out)
{
    __shared__ float sW[64 * 64];
    int tid = threadIdx.x;
    for (int i = tid; i < 4096; i += 256) sW[i] = fo_w[i];
    int d = tid & 63, grp = tid >> 6;
    float rb = fo_b[d], rg = fo_g[d], rbt = fo_bt[d];
    __syncthreads();
    for (int n = blockIdx.x * 4 + grp; n < N_; n += gridDim.x * 4) {
        float cm = (float)max(cntm[n], 1);
        size_t o = (size_t)n * 64 + d;
        float r = cent[o] + subp[o] * (1.f / 20.f) + ctxp[o] / cm;
        float dot = rb;
        #pragma unroll
        for (int k = 0; k < 64; k++) dot += __shfl(r, k) * sW[k * 64 + d];
        out[o] = rg * dot + rbt;
    }
}

// ---------------- launch ----------------
extern "C" void kernel_launch(void* const* d_in, const int* in_sizes, int n_in,
                              void* d_out, int out_size, void* d_ws, size_t ws_size,
                              hipStream_t stream) {
    const float* x         = (const float*)d_in[0];
    const float* edge_attr = (const float*)d_in[1];
    const float* hop_table = (const float*)d_in[2];
    const float* conv_w1   = (const float*)d_in[3];
    const float* bn1_g     = (const float*)d_in[4];
    const float* bn1_b     = (const float*)d_in[5];
    const float* conv_w2   = (const float*)d_in[6];
    const float* bn2_g     = (const float*)d_in[7];
    const float* bn2_b     = (const float*)d_in[8];
    const float* oe_w      = (const float*)d_in[9];
    const float* oe_b      = (const float*)d_in[10];
    const float* sub_w     = (const float*)d_in[11];
    const float* sub_b     = (const float*)d_in[12];
    const float* sub_g     = (const float*)d_in[13];
    const float* sub_bt    = (const float*)d_in[14];
    const float* ctx_w     = (const float*)d_in[15];
    const float* ctx_b     = (const float*)d_in[16];
    const float* ctx_g     = (const float*)d_in[17];
    const float* ctx_bt    = (const float*)d_in[18];
    const float* gc_w      = (const float*)d_in[19];
    const float* gc_b      = (const float*)d_in[20];
    const float* gs_w      = (const float*)d_in[21];
    const float* gs_b      = (const float*)d_in[22];
    const float* gx_w      = (const float*)d_in[23];
    const float* gx_b      = (const float*)d_in[24];
    const float* fo_w      = (const float*)d_in[25];
    const float* fo_b      = (const float*)d_in[26];
    const float* fo_g      = (const float*)d_in[27];
    const float* fo_bt     = (const float*)d_in[28];
    const int* nodes_mapper  = (const int*)d_in[29];
    const int* edges_mapper  = (const int*)d_in[30];
    const int* edge_index    = (const int*)d_in[31];
    const int* batch         = (const int*)d_in[32];
    const int* hop_indicator = (const int*)d_in[33];
    (void)batch;
    float* out = (float*)d_out;

    // workspace bump allocator (256B aligned) — total ~163 MB
    size_t off = 0;
    auto alloc = [&](size_t bytes) -> char* {
        char* p = (char*)d_ws + off;
        off = (off + bytes + 255) & ~(size_t)255;
        return p;
    };
    unsigned* hbuf0 = (unsigned*)alloc((size_t)NC_ * 40 * 4);  // 64 MB (bf16 pairs)
    unsigned* hbuf1 = (unsigned*)alloc((size_t)NC_ * 40 * 4);  // 64 MB
    int*   start  = (int*)alloc((size_t)(NC_ + 1) * 4);
    int*   cursor = (int*)alloc((size_t)NC_ * 4);
    int*   bsums  = (int*)alloc(2048 * 4);
    int2*  e2     = (int2*)alloc((size_t)EC_ * 8);             // 16 MB
    float* cent   = (float*)alloc((size_t)N_ * 64 * 4);        // 5.12 MB
    float* subp   = (float*)alloc((size_t)N_ * 64 * 4);
    float* ctxp   = (float*)alloc((size_t)N_ * 64 * 4);
    int*   cntm   = (int*)alloc((size_t)N_ * 4);
    (void)ws_size; (void)in_sizes; (void)n_in; (void)out_size;

    // zero only what accumulates via atomics
    hipMemsetAsync(cursor, 0, (size_t)NC_ * 4, stream);
    hipMemsetAsync(ctxp, 0, (size_t)N_ * 64 * 4, stream);
    hipMemsetAsync(cntm, 0, (size_t)N_ * 4, stream);

    // h0 (bf16) + CSR + mapper histogram
    k_build_h0<<<(NC_ * 40 + 255) / 256, 256, 0, stream>>>(hbuf0, x, hop_table,
                                                           nodes_mapper, hop_indicator);
    k_degree<<<(EC_ + 255) / 256, 256, 0, stream>>>(edge_index, cursor);
    k_bsum<<<NB_, 256, 0, stream>>>(cursor, bsums);
    k_scan_bsums<<<1, 256, 0, stream>>>(bsums);
    k_scan_apply<<<NB_, 256, 0, stream>>>(cursor, start, bsums);
    k_fill<<<(EC_ + 255) / 256, 256, 0, stream>>>(edge_index, edges_mapper, cursor, e2);
    k_hist<<<(NC_ + 255) / 256, 256, 0, stream>>>(nodes_mapper, cntm);

    // two GINE layers (bf16 h)
    k_gine<<<2048, 320, 0, stream>>>(hbuf0, hbuf1, edge_attr, start, e2, conv_w1, bn1_g, bn1_b);
    k_gine<<<2048, 320, 0, stream>>>(hbuf1, hbuf0, edge_attr, start, e2, conv_w2, bn2_g, bn2_b);

    // head: oe + gates + sub/ctx + pools (subgraph-per-block; subp/cent atomic-free)
    k_head<<<2048, 256, 0, stream>>>(hbuf0, hop_table, hop_indicator, nodes_mapper,
                                     oe_w, oe_b, sub_w, sub_b, sub_g, sub_bt,
                                     ctx_w, ctx_b, ctx_g, ctx_bt,
                                     gc_w, gc_b, gs_w, gs_b, gx_w, gx_b,
                                     cent, subp, ctxp);

    // final combine + out encoder
    k_final<<<1280, 256, 0, stream>>>(cent, subp, ctxp, cntm, fo_w, fo_b, fo_g, fo_bt, out);
}

// Round 4
// 1643.451 us; speedup vs baseline: 4.7158x; 4.7158x over previous
//
#include <hip/hip_runtime.h>
#include <hip/hip_bf16.h>

#define N_    20000
#define S_    20
#define NC_   400000
#define EC_   2000000
#define EB_   200000
#define NIN_  64
#define HOP_  16
#define D_    80
#define NOUT_ 64
#define NB_   1563   // ceil(NC/256)

// ---------------- bf16 pack/unpack (pair layout: lo=feat 2p, hi=feat 2p+1) ----------------
__device__ __forceinline__ float2 bf2f(unsigned u) {
    float2 r;
    r.x = __uint_as_float(u << 16);
    r.y = __uint_as_float(u & 0xffff0000u);
    return r;
}
__device__ __forceinline__ unsigned f2bf_rne(float f) {
    unsigned u = __float_as_uint(f);
    return (u + 0x7fffu + ((u >> 16) & 1u)) >> 16;
}
__device__ __forceinline__ unsigned pack2(float a, float b) {
    return f2bf_rne(a) | (f2bf_rne(b) << 16);
}

// ---------------- scan utility (block of 256 = 4 waves) ----------------
__device__ __forceinline__ int blockExclScan(int v, int tid, int* lds, int* total) {
    int lane = tid & 63;
    int w = tid >> 6;
    int x = v;
    #pragma unroll
    for (int off = 1; off < 64; off <<= 1) {
        int y = __shfl_up(x, off, 64);
        if (lane >= off) x += y;
    }
    if (lane == 63) lds[w] = x;
    __syncthreads();
    if (tid == 0) {
        int acc = 0;
        #pragma unroll
        for (int i = 0; i < 4; i++) { int t = lds[i]; lds[4 + i] = acc; acc += t; }
        lds[8] = acc;
    }
    __syncthreads();
    int res = x - v + lds[4 + w];
    *total = lds[8];
    return res;
}

// ---------------- CSR build ----------------
__global__ __launch_bounds__(256) void k_degree(const int* __restrict__ eidx, int* __restrict__ deg) {
    int e = blockIdx.x * 256 + threadIdx.x;
    if (e >= EC_) return;
    atomicAdd(&deg[eidx[EC_ + e]], 1);
}

__global__ __launch_bounds__(256) void k_bsum(const int* __restrict__ deg, int* __restrict__ bsums) {
    __shared__ int lds[9];
    int i = blockIdx.x * 256 + threadIdx.x;
    int v = (i < NC_) ? deg[i] : 0;
    int tot;
    blockExclScan(v, threadIdx.x, lds, &tot);
    if (threadIdx.x == 0) bsums[blockIdx.x] = tot;
}

__global__ __launch_bounds__(256) void k_scan_bsums(int* __restrict__ bsums) {
    __shared__ int lds[9];
    int carry = 0;
    for (int base = 0; base < NB_; base += 256) {
        int i = base + threadIdx.x;
        int v = (i < NB_) ? bsums[i] : 0;
        int tot;
        int ex = blockExclScan(v, threadIdx.x, lds, &tot);
        if (i < NB_) bsums[i] = ex + carry;
        carry += tot;
        __syncthreads();
    }
}

__global__ __launch_bounds__(256) void k_scan_apply(
    int* __restrict__ cursor, int* __restrict__ start, const int* __restrict__ bsums)
{
    __shared__ int lds[9];
    int i = blockIdx.x * 256 + threadIdx.x;
    int v = (i < NC_) ? cursor[i] : 0;
    int tot;
    int ex = blockExclScan(v, threadIdx.x, lds, &tot);
    if (i < NC_) {
        int s = ex + bsums[blockIdx.x];
        start[i] = s;
        cursor[i] = s;
    }
    if (blockIdx.x == 0 && threadIdx.x == 0) start[NC_] = EC_;
}

__global__ __launch_bounds__(256) void k_fill(
    const int* __restrict__ eidx, const int* __restrict__ emap,
    int* __restrict__ cursor, int2* __restrict__ e2)
{
    int e = blockIdx.x * 256 + threadIdx.x;
    if (e >= EC_) return;
    int src = eidx[e];
    int dst = eidx[EC_ + e];
    int pos = atomicAdd(&cursor[dst], 1);
    e2[pos] = make_int2(src, emap[e]);
}

__global__ __launch_bounds__(256) void k_hist(const int* __restrict__ mapper, int* __restrict__ cntm) {
    int i = blockIdx.x * 256 + threadIdx.x;
    if (i >= NC_) return;
    atomicAdd(&cntm[mapper[i]], 1);
}

// ---------------- h0 = concat(x[mapper], hop_table[hop+1]) as bf16 pairs ----------------
__global__ __launch_bounds__(256) void k_build_h0(
    unsigned* __restrict__ h0, const float* __restrict__ x, const float* __restrict__ ht,
    const int* __restrict__ mapper, const int* __restrict__ hop)
{
    int idx = blockIdx.x * 256 + threadIdx.x;   // NC*40 pair-slots
    if (idx >= NC_ * 40) return;
    int node = idx / 40, t = idx - node * 40;
    float2 v;
    if (t < 32) v = *(const float2*)(x + (size_t)mapper[node] * 64 + 2 * t);
    else        v = *(const float2*)(ht + (size_t)(hop[node] + 1) * 16 + 2 * (t - 32));
    h0[idx] = pack2(v.x, v.y);
}

// ---------------- precompute hop gates: gall[{gc,gs,gx} x 20 x 64] ----------------
__global__ __launch_bounds__(64) void k_gates(
    const float* __restrict__ ht,
    const float* __restrict__ gc_w, const float* __restrict__ gc_b,
    const float* __restrict__ gs_w, const float* __restrict__ gs_b,
    const float* __restrict__ gx_w, const float* __restrict__ gx_b,
    float* __restrict__ gall)
{
    int h = blockIdx.x;        // 0..19
    int d = threadIdx.x;       // 0..63
    const float* htr = ht + h * 16;
    float a = gc_b[d], b = gs_b[d], c = gx_b[d];
    #pragma unroll
    for (int k = 0; k < 16; k++) {
        float hk = htr[k];
        a += hk * gc_w[k * 64 + d];
        b += hk * gs_w[k * 64 + d];
        c += hk * gx_w[k * 64 + d];
    }
    gall[h * 64 + d]            = 1.f / (1.f + __expf(-a));
    gall[(20 + h) * 64 + d]     = 1.f / (1.f + __expf(-b));
    gall[(40 + h) * 64 + d]     = 1.f / (1.f + __expf(-c));
}

// ---------------- GINE layer (bf16 h in/out, f32 edge_attr, f32 weights) ----------------
// block = 320 = 8 groups x 40 threads; thread owns features (2t, 2t+1) of its node.
__global__ __launch_bounds__(320) void k_gine(
    const unsigned* __restrict__ hin, unsigned* __restrict__ hout,
    const float* __restrict__ ea, const int* __restrict__ start,
    const int2* __restrict__ e2,
    const float* __restrict__ W, const float* __restrict__ g, const float* __restrict__ b)
{
    __shared__ float sW[D_ * D_];      // 25.6 KB
    __shared__ float sV[8][D_ + 2];
    int tid = threadIdx.x;
    for (int t = tid; t < D_ * D_; t += 320) sW[t] = W[t];
    int grp = tid / 40;
    int t = tid - grp * 40;
    float2 gd = *(const float2*)(g + 2 * t);
    float2 bd = *(const float2*)(b + 2 * t);
    __syncthreads();
    for (int chunk = blockIdx.x; chunk < NC_ / 8; chunk += gridDim.x) {
        int node = chunk * 8 + grp;
        float2 hd = bf2f(hin[(size_t)node * 40 + t]);
        float accx = 0.f, accy = 0.f;
        int e = start[node], s1 = start[node + 1];
        for (; e + 4 <= s1; e += 4) {
            int2 a0 = e2[e], a1 = e2[e + 1], a2 = e2[e + 2], a3 = e2[e + 3];
            unsigned u0 = hin[(size_t)a0.x * 40 + t];
            unsigned u1 = hin[(size_t)a1.x * 40 + t];
            unsigned u2 = hin[(size_t)a2.x * 40 + t];
            unsigned u3 = hin[(size_t)a3.x * 40 + t];
            float2 q0 = *(const float2*)(ea + (size_t)a0.y * D_ + 2 * t);
            float2 q1 = *(const float2*)(ea + (size_t)a1.y * D_ + 2 * t);
            float2 q2 = *(const float2*)(ea + (size_t)a2.y * D_ + 2 * t);
            float2 q3 = *(const float2*)(ea + (size_t)a3.y * D_ + 2 * t);
            float2 f0 = bf2f(u0), f1 = bf2f(u1), f2 = bf2f(u2), f3 = bf2f(u3);
            accx += fmaxf(f0.x + q0.x, 0.f) + fmaxf(f1.x + q1.x, 0.f)
                  + fmaxf(f2.x + q2.x, 0.f) + fmaxf(f3.x + q3.x, 0.f);
            accy += fmaxf(f0.y + q0.y, 0.f) + fmaxf(f1.y + q1.y, 0.f)
                  + fmaxf(f2.y + q2.y, 0.f) + fmaxf(f3.y + q3.y, 0.f);
        }
        for (; e < s1; e++) {
            int2 a = e2[e];
            unsigned u = hin[(size_t)a.x * 40 + t];
            float2 q = *(const float2*)(ea + (size_t)a.y * D_ + 2 * t);
            float2 f = bf2f(u);
            accx += fmaxf(f.x + q.x, 0.f);
            accy += fmaxf(f.y + q.y, 0.f);
        }
        sV[grp][2 * t]     = hd.x + accx;
        sV[grp][2 * t + 1] = hd.y + accy;
        __syncthreads();
        float dx = 0.f, dy = 0.f;
        #pragma unroll
        for (int k = 0; k < D_; k++) {
            float v = sV[grp][k];
            float2 w = *(const float2*)(sW + k * D_ + 2 * t);
            dx += v * w.x;
            dy += v * w.y;
        }
        float ox = fmaxf(gd.x * dx + bd.x, 0.f) + hd.x;
        float oy = fmaxf(gd.y * dy + bd.y, 0.f) + hd.y;
        hout[(size_t)node * 40 + t] = pack2(ox, oy);
        __syncthreads();
    }
}

// ---------------- head: oe + gates + sub/ctx + pooling ----------------
// block = 256 = 4 waves; wave w owns subgraph n = blockIdx.x*4 + w (20 nodes); lane = dim d.
// Weights staged in LDS as packed bf16 pairs (k-major pairs): 26.6 KB total.
__global__ __launch_bounds__(256) void k_head(
    const unsigned* __restrict__ h2u, const int* __restrict__ hop,
    const int* __restrict__ mapper, const float* __restrict__ gall,
    const float* __restrict__ oe_w, const float* __restrict__ oe_b,
    const float* __restrict__ sub_w, const float* __restrict__ sub_b,
    const float* __restrict__ sub_g, const float* __restrict__ sub_bt,
    const float* __restrict__ ctx_w, const float* __restrict__ ctx_b,
    const float* __restrict__ ctx_g, const float* __restrict__ ctx_bt,
    float* __restrict__ cent, float* __restrict__ subp, float* __restrict__ ctxp)
{
    __shared__ unsigned sOE[40 * 64];   // packed (oe[2k][d], oe[2k+1][d])
    __shared__ unsigned sSUB[32 * 64];
    __shared__ unsigned sCTX[32 * 64];
    int tid = threadIdx.x;
    for (int i = tid; i < 40 * 64; i += 256) {
        int k = i >> 6, d0 = i & 63;
        sOE[i] = pack2(oe_w[(2 * k) * 64 + d0], oe_w[(2 * k + 1) * 64 + d0]);
    }
    for (int i = tid; i < 32 * 64; i += 256) {
        int k = i >> 6, d0 = i & 63;
        sSUB[i] = pack2(sub_w[(2 * k) * 64 + d0], sub_w[(2 * k + 1) * 64 + d0]);
        sCTX[i] = pack2(ctx_w[(2 * k) * 64 + d0], ctx_w[(2 * k + 1) * 64 + d0]);
    }
    int d = tid & 63;
    int w = tid >> 6;
    float r_oeb = oe_b[d];
    float r_sb = sub_b[d], r_sg = sub_g[d], r_sbt = sub_bt[d];
    float r_cb = ctx_b[d], r_cg = ctx_g[d], r_cbt = ctx_bt[d];
    __syncthreads();

    int n = blockIdx.x * 4 + w;
    if (n >= N_) return;
    float subacc = 0.f;
    for (int i = 0; i < S_; i++) {
        int node = n * S_ + i;
        // lane k<40 holds bf16 pair (feat 2k, 2k+1) of the h2 row
        unsigned rowp = (d < 40) ? h2u[(size_t)node * 40 + d] : 0u;
        // comb = row @ oe_w + oe_b
        float comb = r_oeb;
        #pragma unroll 8
        for (int k = 0; k < 40; k++) {
            float2 f = bf2f(__shfl(rowp, k));
            float2 wv = bf2f(sOE[k * 64 + d]);
            comb += f.x * wv.x + f.y * wv.y;
        }
        int hn = hop[node] + 1;
        float gsv = gall[(20 + hn) * 64 + d];
        float gxv = gall[(40 + hn) * 64 + d];
        // sub / ctx transforms (comb broadcast via shfl)
        float sv = r_sb, cv = r_cb;
        #pragma unroll 8
        for (int k = 0; k < 32; k++) {
            float c0 = __shfl(comb, 2 * k);
            float c1 = __shfl(comb, 2 * k + 1);
            float2 ws = bf2f(sSUB[k * 64 + d]);
            float2 wc = bf2f(sCTX[k * 64 + d]);
            sv += c0 * ws.x + c1 * ws.y;
            cv += c0 * wc.x + c1 * wc.y;
        }
        sv = fmaxf(r_sg * sv + r_sbt, 0.f) * gsv;
        cv = fmaxf(r_cg * cv + r_cbt, 0.f) * gxv;
        subacc += sv;
        int mm = mapper[node];
        atomicAdd(&ctxp[(size_t)mm * 64 + d], cv);
        if (mm == n) cent[(size_t)n * 64 + d] = comb * gall[hn * 64 + d];
    }
    subp[(size_t)n * 64 + d] = subacc;
}

// ---------------- final: combine pools + out_encoder ----------------
__global__ __launch_bounds__(256) void k_final(
    const float* __restrict__ cent, const float* __restrict__ subp, const float* __restrict__ ctxp,
    const int* __restrict__ cntm,
    const float* __restrict__ fo_w, const float* __restrict__ fo_b,
    const float* __restrict__ fo_g, const float* __restrict__ fo_bt,
    float* __restrict__ out)
{
    __shared__ float sW[64 * 64];
    int tid = threadIdx.x;
    for (int i = tid; i < 4096; i += 256) sW[i] = fo_w[i];
    int d = tid & 63, grp = tid >> 6;
    float rb = fo_b[d], rg = fo_g[d], rbt = fo_bt[d];
    __syncthreads();
    for (int n = blockIdx.x * 4 + grp; n < N_; n += gridDim.x * 4) {
        float cm = (float)max(cntm[n], 1);
        size_t o = (size_t)n * 64 + d;
        float r = cent[o] + subp[o] * (1.f / 20.f) + ctxp[o] / cm;
        float dot = rb;
        #pragma unroll 8
        for (int k = 0; k < 64; k++) dot += __shfl(r, k) * sW[k * 64 + d];
        out[o] = rg * dot + rbt;
    }
}

// ---------------- launch ----------------
extern "C" void kernel_launch(void* const* d_in, const int* in_sizes, int n_in,
                              void* d_out, int out_size, void* d_ws, size_t ws_size,
                              hipStream_t stream) {
    const float* x         = (const float*)d_in[0];
    const float* edge_attr = (const float*)d_in[1];
    const float* hop_table = (const float*)d_in[2];
    const float* conv_w1   = (const float*)d_in[3];
    const float* bn1_g     = (const float*)d_in[4];
    const float* bn1_b     = (const float*)d_in[5];
    const float* conv_w2   = (const float*)d_in[6];
    const float* bn2_g     = (const float*)d_in[7];
    const float* bn2_b     = (const float*)d_in[8];
    const float* oe_w      = (const float*)d_in[9];
    const float* oe_b      = (const float*)d_in[10];
    const float* sub_w     = (const float*)d_in[11];
    const float* sub_b     = (const float*)d_in[12];
    const float* sub_g     = (const float*)d_in[13];
    const float* sub_bt    = (const float*)d_in[14];
    const float* ctx_w     = (const float*)d_in[15];
    const float* ctx_b     = (const float*)d_in[16];
    const float* ctx_g     = (const float*)d_in[17];
    const float* ctx_bt    = (const float*)d_in[18];
    const float* gc_w      = (const float*)d_in[19];
    const float* gc_b      = (const float*)d_in[20];
    const float* gs_w      = (const float*)d_in[21];
    const float* gs_b      = (const float*)d_in[22];
    const float* gx_w      = (const float*)d_in[23];
    const float* gx_b      = (const float*)d_in[24];
    const float* fo_w      = (const float*)d_in[25];
    const float* fo_b      = (const float*)d_in[26];
    const float* fo_g      = (const float*)d_in[27];
    const float* fo_bt     = (const float*)d_in[28];
    const int* nodes_mapper  = (const int*)d_in[29];
    const int* edges_mapper  = (const int*)d_in[30];
    const int* edge_index    = (const int*)d_in[31];
    const int* batch         = (const int*)d_in[32];
    const int* hop_indicator = (const int*)d_in[33];
    (void)batch;
    float* out = (float*)d_out;

    // workspace bump allocator (256B aligned) — total ~163 MB
    size_t off = 0;
    auto alloc = [&](size_t bytes) -> char* {
        char* p = (char*)d_ws + off;
        off = (off + bytes + 255) & ~(size_t)255;
        return p;
    };
    unsigned* hbuf0 = (unsigned*)alloc((size_t)NC_ * 40 * 4);  // 64 MB (bf16 pairs)
    unsigned* hbuf1 = (unsigned*)alloc((size_t)NC_ * 40 * 4);  // 64 MB
    int*   start  = (int*)alloc((size_t)(NC_ + 1) * 4);
    int*   cursor = (int*)alloc((size_t)NC_ * 4);
    int*   bsums  = (int*)alloc(2048 * 4);
    int2*  e2     = (int2*)alloc((size_t)EC_ * 8);             // 16 MB
    float* cent   = (float*)alloc((size_t)N_ * 64 * 4);        // 5.12 MB
    float* subp   = (float*)alloc((size_t)N_ * 64 * 4);
    float* ctxp   = (float*)alloc((size_t)N_ * 64 * 4);
    int*   cntm   = (int*)alloc((size_t)N_ * 4);
    float* gall   = (float*)alloc((size_t)60 * 64 * 4);        // 15 KB gate table
    (void)ws_size; (void)in_sizes; (void)n_in; (void)out_size;

    // zero only what accumulates via atomics
    hipMemsetAsync(cursor, 0, (size_t)NC_ * 4, stream);
    hipMemsetAsync(ctxp, 0, (size_t)N_ * 64 * 4, stream);
    hipMemsetAsync(cntm, 0, (size_t)N_ * 4, stream);

    // h0 (bf16) + CSR + mapper histogram + gate table
    k_build_h0<<<(NC_ * 40 + 255) / 256, 256, 0, stream>>>(hbuf0, x, hop_table,
                                                           nodes_mapper, hop_indicator);
    k_degree<<<(EC_ + 255) / 256, 256, 0, stream>>>(edge_index, cursor);
    k_bsum<<<NB_, 256, 0, stream>>>(cursor, bsums);
    k_scan_bsums<<<1, 256, 0, stream>>>(bsums);
    k_scan_apply<<<NB_, 256, 0, stream>>>(cursor, start, bsums);
    k_fill<<<(EC_ + 255) / 256, 256, 0, stream>>>(edge_index, edges_mapper, cursor, e2);
    k_hist<<<(NC_ + 255) / 256, 256, 0, stream>>>(nodes_mapper, cntm);
    k_gates<<<20, 64, 0, stream>>>(hop_table, gc_w, gc_b, gs_w, gs_b, gx_w, gx_b, gall);

    // two GINE layers (bf16 h)
    k_gine<<<2048, 320, 0, stream>>>(hbuf0, hbuf1, edge_attr, start, e2, conv_w1, bn1_g, bn1_b);
    k_gine<<<2048, 320, 0, stream>>>(hbuf1, hbuf0, edge_attr, start, e2, conv_w2, bn2_g, bn2_b);

    // head: one wave per subgraph; subp/cent atomic-free
    k_head<<<N_ / 4, 256, 0, stream>>>(hbuf0, hop_indicator, nodes_mapper, gall,
                                       oe_w, oe_b, sub_w, sub_b, sub_g, sub_bt,
                                       ctx_w, ctx_b, ctx_g, ctx_bt,
                                       cent, subp, ctxp);

    // final combine + out encoder
    k_final<<<1280, 256, 0, stream>>>(cent, subp, ctxp, cntm, fo_w, fo_b, fo_g, fo_bt, out);
}

// Round 5
// 1456.514 us; speedup vs baseline: 5.3211x; 1.1283x over previous
//
#include <hip/hip_runtime.h>
#include <hip/hip_bf16.h>

#define N_    20000
#define S_    20
#define NC_   400000
#define EC_   2000000
#define EB_   200000
#define NIN_  64
#define HOP_  16
#define D_    80
#define NOUT_ 64
#define NB_   1563   // ceil(NC/256)

typedef __attribute__((ext_vector_type(8))) short bf16x8;
typedef __attribute__((ext_vector_type(4))) float f32x4;
union FragU { uint4 u; bf16x8 b; };

// ---------------- bf16 pack/unpack (pair layout: lo=feat 2p, hi=feat 2p+1) ----------------
__device__ __forceinline__ float2 bf2f(unsigned u) {
    float2 r;
    r.x = __uint_as_float(u << 16);
    r.y = __uint_as_float(u & 0xffff0000u);
    return r;
}
__device__ __forceinline__ unsigned f2bf_rne(float f) {
    unsigned u = __float_as_uint(f);
    return (u + 0x7fffu + ((u >> 16) & 1u)) >> 16;
}
__device__ __forceinline__ unsigned pack2(float a, float b) {
    return f2bf_rne(a) | (f2bf_rne(b) << 16);
}

// ---------------- scan utility (block of 256 = 4 waves) ----------------
__device__ __forceinline__ int blockExclScan(int v, int tid, int* lds, int* total) {
    int lane = tid & 63;
    int w = tid >> 6;
    int x = v;
    #pragma unroll
    for (int off = 1; off < 64; off <<= 1) {
        int y = __shfl_up(x, off, 64);
        if (lane >= off) x += y;
    }
    if (lane == 63) lds[w] = x;
    __syncthreads();
    if (tid == 0) {
        int acc = 0;
        #pragma unroll
        for (int i = 0; i < 4; i++) { int t = lds[i]; lds[4 + i] = acc; acc += t; }
        lds[8] = acc;
    }
    __syncthreads();
    int res = x - v + lds[4 + w];
    *total = lds[8];
    return res;
}

// ---------------- CSR build ----------------
__global__ __launch_bounds__(256) void k_degree(const int* __restrict__ eidx, int* __restrict__ deg) {
    int e = blockIdx.x * 256 + threadIdx.x;
    if (e >= EC_) return;
    atomicAdd(&deg[eidx[EC_ + e]], 1);
}

__global__ __launch_bounds__(256) void k_bsum(const int* __restrict__ deg, int* __restrict__ bsums) {
    __shared__ int lds[9];
    int i = blockIdx.x * 256 + threadIdx.x;
    int v = (i < NC_) ? deg[i] : 0;
    int tot;
    blockExclScan(v, threadIdx.x, lds, &tot);
    if (threadIdx.x == 0) bsums[blockIdx.x] = tot;
}

__global__ __launch_bounds__(256) void k_scan_bsums(int* __restrict__ bsums) {
    __shared__ int lds[9];
    int carry = 0;
    for (int base = 0; base < NB_; base += 256) {
        int i = base + threadIdx.x;
        int v = (i < NB_) ? bsums[i] : 0;
        int tot;
        int ex = blockExclScan(v, threadIdx.x, lds, &tot);
        if (i < NB_) bsums[i] = ex + carry;
        carry += tot;
        __syncthreads();
    }
}

__global__ __launch_bounds__(256) void k_scan_apply(
    int* __restrict__ cursor, int* __restrict__ start, const int* __restrict__ bsums)
{
    __shared__ int lds[9];
    int i = blockIdx.x * 256 + threadIdx.x;
    int v = (i < NC_) ? cursor[i] : 0;
    int tot;
    int ex = blockExclScan(v, threadIdx.x, lds, &tot);
    if (i < NC_) {
        int s = ex + bsums[blockIdx.x];
        start[i] = s;
        cursor[i] = s;
    }
    if (blockIdx.x == 0 && threadIdx.x == 0) start[NC_] = EC_;
}

__global__ __launch_bounds__(256) void k_fill(
    const int* __restrict__ eidx, const int* __restrict__ emap,
    int* __restrict__ cursor, int2* __restrict__ e2)
{
    int e = blockIdx.x * 256 + threadIdx.x;
    if (e >= EC_) return;
    int src = eidx[e];
    int dst = eidx[EC_ + e];
    int pos = atomicAdd(&cursor[dst], 1);
    e2[pos] = make_int2(src, emap[e]);
}

__global__ __launch_bounds__(256) void k_hist(const int* __restrict__ mapper, int* __restrict__ cntm) {
    int i = blockIdx.x * 256 + threadIdx.x;
    if (i >= NC_) return;
    atomicAdd(&cntm[mapper[i]], 1);
}

// ---------------- h0 = concat(x[mapper], hop_table[hop+1]) as bf16 pairs ----------------
__global__ __launch_bounds__(256) void k_build_h0(
    unsigned* __restrict__ h0, const float* __restrict__ x, const float* __restrict__ ht,
    const int* __restrict__ mapper, const int* __restrict__ hop)
{
    int idx = blockIdx.x * 256 + threadIdx.x;   // NC*40 pair-slots
    if (idx >= NC_ * 40) return;
    int node = idx / 40, t = idx - node * 40;
    float2 v;
    if (t < 32) v = *(const float2*)(x + (size_t)mapper[node] * 64 + 2 * t);
    else        v = *(const float2*)(ht + (size_t)(hop[node] + 1) * 16 + 2 * (t - 32));
    h0[idx] = pack2(v.x, v.y);
}

// ---------------- precompute hop gates: gall[{gc,gs,gx} x 20 x 64] ----------------
__global__ __launch_bounds__(64) void k_gates(
    const float* __restrict__ ht,
    const float* __restrict__ gc_w, const float* __restrict__ gc_b,
    const float* __restrict__ gs_w, const float* __restrict__ gs_b,
    const float* __restrict__ gx_w, const float* __restrict__ gx_b,
    float* __restrict__ gall)
{
    int h = blockIdx.x;        // 0..19
    int d = threadIdx.x;       // 0..63
    const float* htr = ht + h * 16;
    float a = gc_b[d], b = gs_b[d], c = gx_b[d];
    #pragma unroll
    for (int k = 0; k < 16; k++) {
        float hk = htr[k];
        a += hk * gc_w[k * 64 + d];
        b += hk * gs_w[k * 64 + d];
        c += hk * gx_w[k * 64 + d];
    }
    gall[h * 64 + d]            = 1.f / (1.f + __expf(-a));
    gall[(20 + h) * 64 + d]     = 1.f / (1.f + __expf(-b));
    gall[(40 + h) * 64 + d]     = 1.f / (1.f + __expf(-c));
}

// ---------------- GINE layer (bf16 h in/out, f32 edge_attr, f32 weights) ----------------
__global__ __launch_bounds__(320) void k_gine(
    const unsigned* __restrict__ hin, unsigned* __restrict__ hout,
    const float* __restrict__ ea, const int* __restrict__ start,
    const int2* __restrict__ e2,
    const float* __restrict__ W, const float* __restrict__ g, const float* __restrict__ b)
{
    __shared__ float sW[D_ * D_];      // 25.6 KB
    __shared__ float sV[8][D_ + 2];
    int tid = threadIdx.x;
    for (int t = tid; t < D_ * D_; t += 320) sW[t] = W[t];
    int grp = tid / 40;
    int t = tid - grp * 40;
    float2 gd = *(const float2*)(g + 2 * t);
    float2 bd = *(const float2*)(b + 2 * t);
    __syncthreads();
    for (int chunk = blockIdx.x; chunk < NC_ / 8; chunk += gridDim.x) {
        int node = chunk * 8 + grp;
        float2 hd = bf2f(hin[(size_t)node * 40 + t]);
        float accx = 0.f, accy = 0.f;
        int e = start[node], s1 = start[node + 1];
        for (; e + 4 <= s1; e += 4) {
            int2 a0 = e2[e], a1 = e2[e + 1], a2 = e2[e + 2], a3 = e2[e + 3];
            unsigned u0 = hin[(size_t)a0.x * 40 + t];
            unsigned u1 = hin[(size_t)a1.x * 40 + t];
            unsigned u2 = hin[(size_t)a2.x * 40 + t];
            unsigned u3 = hin[(size_t)a3.x * 40 + t];
            float2 q0 = *(const float2*)(ea + (size_t)a0.y * D_ + 2 * t);
            float2 q1 = *(const float2*)(ea + (size_t)a1.y * D_ + 2 * t);
            float2 q2 = *(const float2*)(ea + (size_t)a2.y * D_ + 2 * t);
            float2 q3 = *(const float2*)(ea + (size_t)a3.y * D_ + 2 * t);
            float2 f0 = bf2f(u0), f1 = bf2f(u1), f2 = bf2f(u2), f3 = bf2f(u3);
            accx += fmaxf(f0.x + q0.x, 0.f) + fmaxf(f1.x + q1.x, 0.f)
                  + fmaxf(f2.x + q2.x, 0.f) + fmaxf(f3.x + q3.x, 0.f);
            accy += fmaxf(f0.y + q0.y, 0.f) + fmaxf(f1.y + q1.y, 0.f)
                  + fmaxf(f2.y + q2.y, 0.f) + fmaxf(f3.y + q3.y, 0.f);
        }
        for (; e < s1; e++) {
            int2 a = e2[e];
            unsigned u = hin[(size_t)a.x * 40 + t];
            float2 q = *(const float2*)(ea + (size_t)a.y * D_ + 2 * t);
            float2 f = bf2f(u);
            accx += fmaxf(f.x + q.x, 0.f);
            accy += fmaxf(f.y + q.y, 0.f);
        }
        sV[grp][2 * t]     = hd.x + accx;
        sV[grp][2 * t + 1] = hd.y + accy;
        __syncthreads();
        float dx = 0.f, dy = 0.f;
        #pragma unroll
        for (int k = 0; k < D_; k++) {
            float v = sV[grp][k];
            float2 w = *(const float2*)(sW + k * D_ + 2 * t);
            dx += v * w.x;
            dy += v * w.y;
        }
        float ox = fmaxf(gd.x * dx + bd.x, 0.f) + hd.x;
        float oy = fmaxf(gd.y * dy + bd.y, 0.f) + hd.y;
        hout[(size_t)node * 40 + t] = pack2(ox, oy);
        __syncthreads();
    }
}

// ---------------- MFMA head: oe + gates + sub/ctx + pooling ----------------
// block = 256 = 4 waves; wave owns a 16-node tile. grid = NC/(16*4) = 6250.
// Fragment layouts (mfma_f32_16x16x32_bf16):
//   A: row = lane%16, k = 8*(lane/16)+j     B: k = 8*(lane/16)+j, col = lane%16
//   D: col = lane%16, row = 4*(lane/16)+reg
__global__ __launch_bounds__(256) void k_headm(
    const unsigned* __restrict__ h2u, const int* __restrict__ hop,
    const int* __restrict__ mapper, const float* __restrict__ gall,
    const float* __restrict__ oe_w, const float* __restrict__ oe_b,
    const float* __restrict__ sub_w, const float* __restrict__ sub_b,
    const float* __restrict__ sub_g, const float* __restrict__ sub_bt,
    const float* __restrict__ ctx_w, const float* __restrict__ ctx_b,
    const float* __restrict__ ctx_g, const float* __restrict__ ctx_bt,
    float* __restrict__ cent, float* __restrict__ subp, float* __restrict__ ctxp)
{
    // B-fragments pre-swizzled: [t][c][kp] with kp = k/2 (u32 = bf16 pair along k)
    __shared__ unsigned sOE[4 * 16 * 48];   // 12 KB (kp 0..39 data, pad->48 for stride)
    __shared__ unsigned sSB[4 * 16 * 40];   // 10 KB (kp 0..31 data, pad->40)
    __shared__ unsigned sCX[4 * 16 * 40];   // 10 KB
    __shared__ float    sT[4][16 * 68];     // 17 KB  D->A transpose buffer (stride 68)
    int tid = threadIdx.x;
    for (int i = tid; i < 4 * 16 * 48; i += 256) {
        int t = i / (16 * 48), r2 = i % (16 * 48), cc = r2 / 48, kp = r2 % 48;
        int col = 16 * t + cc;
        sOE[i] = (kp < 40) ? pack2(oe_w[(2 * kp) * 64 + col], oe_w[(2 * kp + 1) * 64 + col]) : 0u;
    }
    for (int i = tid; i < 4 * 16 * 40; i += 256) {
        int t = i / (16 * 40), r2 = i % (16 * 40), cc = r2 / 40, kp = r2 % 40;
        int col = 16 * t + cc;
        bool ok = kp < 32;
        sSB[i] = ok ? pack2(sub_w[(2 * kp) * 64 + col], sub_w[(2 * kp + 1) * 64 + col]) : 0u;
        sCX[i] = ok ? pack2(ctx_w[(2 * kp) * 64 + col], ctx_w[(2 * kp + 1) * 64 + col]) : 0u;
    }
    __syncthreads();

    int w = tid >> 6;
    int lane = tid & 63;
    int q = lane >> 4;        // 0..3
    int c = lane & 15;        // 0..15
    int base = (blockIdx.x * 4 + w) * 16;

    // ---- A fragments: h2 rows (row = c), K=80 in 3 steps (last zero-padded) ----
    const uint4* hrow = (const uint4*)(h2u + (size_t)(base + c) * 40);  // 10 uint4/row
    FragU a0, a1, a2;
    a0.u = hrow[q];
    a1.u = hrow[4 + q];
    a2.u = make_uint4(0u, 0u, 0u, 0u);
    if (q < 2) a2.u = hrow[8 + q];

    // ---- comb = h2 @ oe_w  (12 MFMA) ----
    f32x4 acc[4];
    #pragma unroll
    for (int t = 0; t < 4; t++) {
        const unsigned* pb = sOE + (t * 16 + c) * 48 + 4 * q;
        FragU b0, b1, b2;
        b0.u = *(const uint4*)(pb);
        b1.u = *(const uint4*)(pb + 16);
        b2.u = *(const uint4*)(pb + 32);
        f32x4 z = {0.f, 0.f, 0.f, 0.f};
        acc[t] = __builtin_amdgcn_mfma_f32_16x16x32_bf16(a0.b, b0.b, z, 0, 0, 0);
        acc[t] = __builtin_amdgcn_mfma_f32_16x16x32_bf16(a1.b, b1.b, acc[t], 0, 0, 0);
        acc[t] = __builtin_amdgcn_mfma_f32_16x16x32_bf16(a2.b, b2.b, acc[t], 0, 0, 0);
    }

    // ---- per-row metadata (rows 4q+reg) ----
    int mm[4], hn[4], sg[4];
    #pragma unroll
    for (int r = 0; r < 4; r++) {
        int node = base + 4 * q + r;
        mm[r] = mapper[node];
        hn[r] = hop[node] + 1;
        sg[r] = node / S_;      // == batch[node]
    }

    // ---- bias, centroid store, write comb to transpose buffer ----
    #pragma unroll
    for (int t = 0; t < 4; t++) {
        int col = 16 * t + c;
        float ob = oe_b[col];
        #pragma unroll
        for (int r = 0; r < 4; r++) {
            float v = acc[t][r] + ob;
            sT[w][(4 * q + r) * 68 + col] = v;
            if (mm[r] == sg[r]) {
                cent[(size_t)sg[r] * 64 + col] = v * gall[hn[r] * 64 + col];
            }
        }
    }

    // ---- read back as A' fragments (row = c, k' = 32s' + 8q + j), cvt to bf16 ----
    const float* trp = &sT[w][c * 68 + 8 * q];
    float4 v0 = *(const float4*)(trp);
    float4 v1 = *(const float4*)(trp + 4);
    float4 v2 = *(const float4*)(trp + 32);
    float4 v3 = *(const float4*)(trp + 36);
    FragU ap0, ap1;
    ap0.u = make_uint4(pack2(v0.x, v0.y), pack2(v0.z, v0.w), pack2(v1.x, v1.y), pack2(v1.z, v1.w));
    ap1.u = make_uint4(pack2(v2.x, v2.y), pack2(v2.z, v2.w), pack2(v3.x, v3.y), pack2(v3.z, v3.w));

    // ---- sub/ctx GEMMs (16 MFMA) ----
    f32x4 sa[4], ca[4];
    #pragma unroll
    for (int t = 0; t < 4; t++) {
        const unsigned* ps = sSB + (t * 16 + c) * 40 + 4 * q;
        const unsigned* pc = sCX + (t * 16 + c) * 40 + 4 * q;
        FragU b0, b1, d0, d1;
        b0.u = *(const uint4*)(ps);
        b1.u = *(const uint4*)(ps + 16);
        d0.u = *(const uint4*)(pc);
        d1.u = *(const uint4*)(pc + 16);
        f32x4 z = {0.f, 0.f, 0.f, 0.f};
        sa[t] = __builtin_amdgcn_mfma_f32_16x16x32_bf16(ap0.b, b0.b, z, 0, 0, 0);
        sa[t] = __builtin_amdgcn_mfma_f32_16x16x32_bf16(ap1.b, b1.b, sa[t], 0, 0, 0);
        ca[t] = __builtin_amdgcn_mfma_f32_16x16x32_bf16(ap0.b, d0.b, z, 0, 0, 0);
        ca[t] = __builtin_amdgcn_mfma_f32_16x16x32_bf16(ap1.b, d1.b, ca[t], 0, 0, 0);
    }

    // ---- epilogue: BN + ReLU + gates, scatter to pools ----
    #pragma unroll
    for (int t = 0; t < 4; t++) {
        int col = 16 * t + c;
        float sb = sub_b[col], sgm = sub_g[col], sbt = sub_bt[col];
        float cb = ctx_b[col], cgm = ctx_g[col], cbt = ctx_bt[col];
        #pragma unroll
        for (int r = 0; r < 4; r++) {
            float sval = fmaxf(sgm * (sa[t][r] + sb) + sbt, 0.f) * gall[(20 + hn[r]) * 64 + col];
            float cval = fmaxf(cgm * (ca[t][r] + cb) + cbt, 0.f) * gall[(40 + hn[r]) * 64 + col];
            atomicAdd(&subp[(size_t)sg[r] * 64 + col], sval);
            atomicAdd(&ctxp[(size_t)mm[r] * 64 + col], cval);
        }
    }
}

// ---------------- final: combine pools + out_encoder ----------------
__global__ __launch_bounds__(256) void k_final(
    const float* __restrict__ cent, const float* __restrict__ subp, const float* __restrict__ ctxp,
    const int* __restrict__ cntm,
    const float* __restrict__ fo_w, const float* __restrict__ fo_b,
    const float* __restrict__ fo_g, const float* __restrict__ fo_bt,
    float* __restrict__ out)
{
    __shared__ float sW[64 * 64];
    int tid = threadIdx.x;
    for (int i = tid; i < 4096; i += 256) sW[i] = fo_w[i];
    int d = tid & 63, grp = tid >> 6;
    float rb = fo_b[d], rg = fo_g[d], rbt = fo_bt[d];
    __syncthreads();
    for (int n = blockIdx.x * 4 + grp; n < N_; n += gridDim.x * 4) {
        float cm = (float)max(cntm[n], 1);
        size_t o = (size_t)n * 64 + d;
        float r = cent[o] + subp[o] * (1.f / 20.f) + ctxp[o] / cm;
        float dot = rb;
        #pragma unroll 8
        for (int k = 0; k < 64; k++) dot += __shfl(r, k) * sW[k * 64 + d];
        out[o] = rg * dot + rbt;
    }
}

// ---------------- launch ----------------
extern "C" void kernel_launch(void* const* d_in, const int* in_sizes, int n_in,
                              void* d_out, int out_size, void* d_ws, size_t ws_size,
                              hipStream_t stream) {
    const float* x         = (const float*)d_in[0];
    const float* edge_attr = (const float*)d_in[1];
    const float* hop_table = (const float*)d_in[2];
    const float* conv_w1   = (const float*)d_in[3];
    const float* bn1_g     = (const float*)d_in[4];
    const float* bn1_b     = (const float*)d_in[5];
    const float* conv_w2   = (const float*)d_in[6];
    const float* bn2_g     = (const float*)d_in[7];
    const float* bn2_b     = (const float*)d_in[8];
    const float* oe_w      = (const float*)d_in[9];
    const float* oe_b      = (const float*)d_in[10];
    const float* sub_w     = (const float*)d_in[11];
    const float* sub_b     = (const float*)d_in[12];
    const float* sub_g     = (const float*)d_in[13];
    const float* sub_bt    = (const float*)d_in[14];
    const float* ctx_w     = (const float*)d_in[15];
    const float* ctx_b     = (const float*)d_in[16];
    const float* ctx_g     = (const float*)d_in[17];
    const float* ctx_bt    = (const float*)d_in[18];
    const float* gc_w      = (const float*)d_in[19];
    const float* gc_b      = (const float*)d_in[20];
    const float* gs_w      = (const float*)d_in[21];
    const float* gs_b      = (const float*)d_in[22];
    const float* gx_w      = (const float*)d_in[23];
    const float* gx_b      = (const float*)d_in[24];
    const float* fo_w      = (const float*)d_in[25];
    const float* fo_b      = (const float*)d_in[26];
    const float* fo_g      = (const float*)d_in[27];
    const float* fo_bt     = (const float*)d_in[28];
    const int* nodes_mapper  = (const int*)d_in[29];
    const int* edges_mapper  = (const int*)d_in[30];
    const int* edge_index    = (const int*)d_in[31];
    const int* batch         = (const int*)d_in[32];
    const int* hop_indicator = (const int*)d_in[33];
    (void)batch;
    float* out = (float*)d_out;

    // workspace bump allocator (256B aligned) — total ~165 MB
    size_t off = 0;
    auto alloc = [&](size_t bytes) -> char* {
        char* p = (char*)d_ws + off;
        off = (off + bytes + 255) & ~(size_t)255;
        return p;
    };
    unsigned* hbuf0 = (unsigned*)alloc((size_t)NC_ * 40 * 4);  // 64 MB (bf16 pairs)
    unsigned* hbuf1 = (unsigned*)alloc((size_t)NC_ * 40 * 4);  // 64 MB
    int*   start  = (int*)alloc((size_t)(NC_ + 1) * 4);
    int*   cursor = (int*)alloc((size_t)NC_ * 4);
    int*   bsums  = (int*)alloc(2048 * 4);
    int2*  e2     = (int2*)alloc((size_t)EC_ * 8);             // 16 MB
    float* cent   = (float*)alloc((size_t)N_ * 64 * 4);        // 5.12 MB
    float* subp   = (float*)alloc((size_t)N_ * 64 * 4);
    float* ctxp   = (float*)alloc((size_t)N_ * 64 * 4);
    int*   cntm   = (int*)alloc((size_t)N_ * 4);
    float* gall   = (float*)alloc((size_t)60 * 64 * 4);        // 15 KB gate table
    (void)ws_size; (void)in_sizes; (void)n_in; (void)out_size;

    // zero what accumulates via atomics
    hipMemsetAsync(cursor, 0, (size_t)NC_ * 4, stream);
    hipMemsetAsync(subp, 0, (size_t)N_ * 64 * 4, stream);
    hipMemsetAsync(ctxp, 0, (size_t)N_ * 64 * 4, stream);
    hipMemsetAsync(cntm, 0, (size_t)N_ * 4, stream);

    // h0 (bf16) + CSR + mapper histogram + gate table
    k_build_h0<<<(NC_ * 40 + 255) / 256, 256, 0, stream>>>(hbuf0, x, hop_table,
                                                           nodes_mapper, hop_indicator);
    k_degree<<<(EC_ + 255) / 256, 256, 0, stream>>>(edge_index, cursor);
    k_bsum<<<NB_, 256, 0, stream>>>(cursor, bsums);
    k_scan_bsums<<<1, 256, 0, stream>>>(bsums);
    k_scan_apply<<<NB_, 256, 0, stream>>>(cursor, start, bsums);
    k_fill<<<(EC_ + 255) / 256, 256, 0, stream>>>(edge_index, edges_mapper, cursor, e2);
    k_hist<<<(NC_ + 255) / 256, 256, 0, stream>>>(nodes_mapper, cntm);
    k_gates<<<20, 64, 0, stream>>>(hop_table, gc_w, gc_b, gs_w, gs_b, gx_w, gx_b, gall);

    // two GINE layers (bf16 h)
    k_gine<<<2048, 320, 0, stream>>>(hbuf0, hbuf1, edge_attr, start, e2, conv_w1, bn1_g, bn1_b);
    k_gine<<<2048, 320, 0, stream>>>(hbuf1, hbuf0, edge_attr, start, e2, conv_w2, bn2_g, bn2_b);

    // MFMA head: 16-node tile per wave
    k_headm<<<NC_ / 64, 256, 0, stream>>>(hbuf0, hop_indicator, nodes_mapper, gall,
                                          oe_w, oe_b, sub_w, sub_b, sub_g, sub_bt,
                                          ctx_w, ctx_b, ctx_g, ctx_bt,
                                          cent, subp, ctxp);

    // final combine + out encoder
    k_final<<<1280, 256, 0, stream>>>(cent, subp, ctxp, cntm, fo_w, fo_b, fo_g, fo_bt, out);
}

// Round 6
// 1336.705 us; speedup vs baseline: 5.7980x; 1.0896x over previous
//
#include <hip/hip_runtime.h>
#include <hip/hip_bf16.h>

#define N_    20000
#define S_    20
#define NC_   400000
#define EC_   2000000
#define EB_   200000
#define NIN_  64
#define HOP_  16
#define D_    80
#define NOUT_ 64
#define NB_   1563   // ceil(NC/256)
#define NBN_  79     // ceil(N/256)

typedef __attribute__((ext_vector_type(8))) short bf16x8;
typedef __attribute__((ext_vector_type(4))) float f32x4;
union FragU { uint4 u; bf16x8 b; };

// ---------------- bf16 pack/unpack (pair layout: lo=feat 2p, hi=feat 2p+1) ----------------
__device__ __forceinline__ float2 bf2f(unsigned u) {
    float2 r;
    r.x = __uint_as_float(u << 16);
    r.y = __uint_as_float(u & 0xffff0000u);
    return r;
}
__device__ __forceinline__ unsigned f2bf_rne(float f) {
    unsigned u = __float_as_uint(f);
    return (u + 0x7fffu + ((u >> 16) & 1u)) >> 16;
}
__device__ __forceinline__ unsigned pack2(float a, float b) {
    return f2bf_rne(a) | (f2bf_rne(b) << 16);
}

// ---------------- scan utility (block of 256 = 4 waves) ----------------
__device__ __forceinline__ int blockExclScan(int v, int tid, int* lds, int* total) {
    int lane = tid & 63;
    int w = tid >> 6;
    int x = v;
    #pragma unroll
    for (int off = 1; off < 64; off <<= 1) {
        int y = __shfl_up(x, off, 64);
        if (lane >= off) x += y;
    }
    if (lane == 63) lds[w] = x;
    __syncthreads();
    if (tid == 0) {
        int acc = 0;
        #pragma unroll
        for (int i = 0; i < 4; i++) { int t = lds[i]; lds[4 + i] = acc; acc += t; }
        lds[8] = acc;
    }
    __syncthreads();
    int res = x - v + lds[4 + w];
    *total = lds[8];
    return res;
}

// ---------------- CSR build (generic over array length) ----------------
__global__ __launch_bounds__(256) void k_degree(const int* __restrict__ eidx, int* __restrict__ deg) {
    int e = blockIdx.x * 256 + threadIdx.x;
    if (e >= EC_) return;
    atomicAdd(&deg[eidx[EC_ + e]], 1);
}

__global__ __launch_bounds__(256) void k_hist(const int* __restrict__ mapper, int* __restrict__ cnt) {
    int i = blockIdx.x * 256 + threadIdx.x;
    if (i >= NC_) return;
    atomicAdd(&cnt[mapper[i]], 1);
}

__global__ __launch_bounds__(256) void k_bsum(const int* __restrict__ deg, int* __restrict__ bsums, int n) {
    __shared__ int lds[9];
    int i = blockIdx.x * 256 + threadIdx.x;
    int v = (i < n) ? deg[i] : 0;
    int tot;
    blockExclScan(v, threadIdx.x, lds, &tot);
    if (threadIdx.x == 0) bsums[blockIdx.x] = tot;
}

__global__ __launch_bounds__(256) void k_scan_bsums(int* __restrict__ bsums, int nb) {
    __shared__ int lds[9];
    int carry = 0;
    for (int base = 0; base < nb; base += 256) {
        int i = base + threadIdx.x;
        int v = (i < nb) ? bsums[i] : 0;
        int tot;
        int ex = blockExclScan(v, threadIdx.x, lds, &tot);
        if (i < nb) bsums[i] = ex + carry;
        carry += tot;
        __syncthreads();
    }
}

__global__ __launch_bounds__(256) void k_scan_apply(
    int* __restrict__ cursor, int* __restrict__ start, const int* __restrict__ bsums,
    int n, int total)
{
    __shared__ int lds[9];
    int i = blockIdx.x * 256 + threadIdx.x;
    int v = (i < n) ? cursor[i] : 0;
    int tot;
    int ex = blockExclScan(v, threadIdx.x, lds, &tot);
    if (i < n) {
        int s = ex + bsums[blockIdx.x];
        start[i] = s;
        cursor[i] = s;
    }
    if (blockIdx.x == 0 && threadIdx.x == 0) start[n] = total;
}

__global__ __launch_bounds__(256) void k_fill(
    const int* __restrict__ eidx, const int* __restrict__ emap,
    int* __restrict__ cursor, int2* __restrict__ e2)
{
    int e = blockIdx.x * 256 + threadIdx.x;
    if (e >= EC_) return;
    int src = eidx[e];
    int dst = eidx[EC_ + e];
    int pos = atomicAdd(&cursor[dst], 1);
    e2[pos] = make_int2(src, emap[e]);
}

__global__ __launch_bounds__(256) void k_fill_nodes(
    const int* __restrict__ mapper, int* __restrict__ cursor, int* __restrict__ nidx)
{
    int i = blockIdx.x * 256 + threadIdx.x;
    if (i >= NC_) return;
    int pos = atomicAdd(&cursor[mapper[i]], 1);
    nidx[pos] = i;
}

// ---------------- h0 = concat(x[mapper], hop_table[hop+1]) as bf16 pairs ----------------
__global__ __launch_bounds__(256) void k_build_h0(
    unsigned* __restrict__ h0, const float* __restrict__ x, const float* __restrict__ ht,
    const int* __restrict__ mapper, const int* __restrict__ hop)
{
    int idx = blockIdx.x * 256 + threadIdx.x;   // NC*40 pair-slots
    if (idx >= NC_ * 40) return;
    int node = idx / 40, t = idx - node * 40;
    float2 v;
    if (t < 32) v = *(const float2*)(x + (size_t)mapper[node] * 64 + 2 * t);
    else        v = *(const float2*)(ht + (size_t)(hop[node] + 1) * 16 + 2 * (t - 32));
    h0[idx] = pack2(v.x, v.y);
}

// ---------------- edge_attr -> bf16 pairs ----------------
__global__ __launch_bounds__(256) void k_ea16(
    unsigned* __restrict__ eab, const float* __restrict__ ea)
{
    int idx = blockIdx.x * 256 + threadIdx.x;   // EB*40 pair-slots
    if (idx >= EB_ * 40) return;
    int row = idx / 40, t = idx - row * 40;
    float2 v = *(const float2*)(ea + (size_t)row * 80 + 2 * t);
    eab[idx] = pack2(v.x, v.y);
}

// ---------------- precompute hop gates: gall[{gc,gs,gx} x 20 x 64] ----------------
__global__ __launch_bounds__(64) void k_gates(
    const float* __restrict__ ht,
    const float* __restrict__ gc_w, const float* __restrict__ gc_b,
    const float* __restrict__ gs_w, const float* __restrict__ gs_b,
    const float* __restrict__ gx_w, const float* __restrict__ gx_b,
    float* __restrict__ gall)
{
    int h = blockIdx.x;        // 0..19
    int d = threadIdx.x;       // 0..63
    const float* htr = ht + h * 16;
    float a = gc_b[d], b = gs_b[d], c = gx_b[d];
    #pragma unroll
    for (int k = 0; k < 16; k++) {
        float hk = htr[k];
        a += hk * gc_w[k * 64 + d];
        b += hk * gs_w[k * 64 + d];
        c += hk * gx_w[k * 64 + d];
    }
    gall[h * 64 + d]            = 1.f / (1.f + __expf(-a));
    gall[(20 + h) * 64 + d]     = 1.f / (1.f + __expf(-b));
    gall[(40 + h) * 64 + d]     = 1.f / (1.f + __expf(-c));
}

// ---------------- GINE layer (bf16 h in/out, bf16-or-f32 edge_attr) ----------------
template<bool EA16>
__global__ __launch_bounds__(320) void k_gine(
    const unsigned* __restrict__ hin, unsigned* __restrict__ hout,
    const float* __restrict__ eaf, const unsigned* __restrict__ eab,
    const int* __restrict__ start, const int2* __restrict__ e2,
    const float* __restrict__ W, const float* __restrict__ g, const float* __restrict__ b)
{
    __shared__ float sW[D_ * D_];      // 25.6 KB
    __shared__ float sV[8][D_ + 2];
    int tid = threadIdx.x;
    for (int t = tid; t < D_ * D_; t += 320) sW[t] = W[t];
    int grp = tid / 40;
    int t = tid - grp * 40;
    float2 gd = *(const float2*)(g + 2 * t);
    float2 bd = *(const float2*)(b + 2 * t);
    __syncthreads();
    for (int chunk = blockIdx.x; chunk < NC_ / 8; chunk += gridDim.x) {
        int node = chunk * 8 + grp;
        float2 hd = bf2f(hin[(size_t)node * 40 + t]);
        float accx = 0.f, accy = 0.f;
        int e = start[node], s1 = start[node + 1];
        for (; e + 4 <= s1; e += 4) {
            int2 a0 = e2[e], a1 = e2[e + 1], a2 = e2[e + 2], a3 = e2[e + 3];
            unsigned u0 = hin[(size_t)a0.x * 40 + t];
            unsigned u1 = hin[(size_t)a1.x * 40 + t];
            unsigned u2 = hin[(size_t)a2.x * 40 + t];
            unsigned u3 = hin[(size_t)a3.x * 40 + t];
            float2 q0, q1, q2, q3;
            if (EA16) {
                q0 = bf2f(eab[(size_t)a0.y * 40 + t]);
                q1 = bf2f(eab[(size_t)a1.y * 40 + t]);
                q2 = bf2f(eab[(size_t)a2.y * 40 + t]);
                q3 = bf2f(eab[(size_t)a3.y * 40 + t]);
            } else {
                q0 = *(const float2*)(eaf + (size_t)a0.y * D_ + 2 * t);
                q1 = *(const float2*)(eaf + (size_t)a1.y * D_ + 2 * t);
                q2 = *(const float2*)(eaf + (size_t)a2.y * D_ + 2 * t);
                q3 = *(const float2*)(eaf + (size_t)a3.y * D_ + 2 * t);
            }
            float2 f0 = bf2f(u0), f1 = bf2f(u1), f2 = bf2f(u2), f3 = bf2f(u3);
            accx += fmaxf(f0.x + q0.x, 0.f) + fmaxf(f1.x + q1.x, 0.f)
                  + fmaxf(f2.x + q2.x, 0.f) + fmaxf(f3.x + q3.x, 0.f);
            accy += fmaxf(f0.y + q0.y, 0.f) + fmaxf(f1.y + q1.y, 0.f)
                  + fmaxf(f2.y + q2.y, 0.f) + fmaxf(f3.y + q3.y, 0.f);
        }
        for (; e < s1; e++) {
            int2 a = e2[e];
            unsigned u = hin[(size_t)a.x * 40 + t];
            float2 q;
            if (EA16) q = bf2f(eab[(size_t)a.y * 40 + t]);
            else      q = *(const float2*)(eaf + (size_t)a.y * D_ + 2 * t);
            float2 f = bf2f(u);
            accx += fmaxf(f.x + q.x, 0.f);
            accy += fmaxf(f.y + q.y, 0.f);
        }
        sV[grp][2 * t]     = hd.x + accx;
        sV[grp][2 * t + 1] = hd.y + accy;
        __syncthreads();
        float dx = 0.f, dy = 0.f;
        #pragma unroll
        for (int k = 0; k < D_; k++) {
            float v = sV[grp][k];
            float2 w = *(const float2*)(sW + k * D_ + 2 * t);
            dx += v * w.x;
            dy += v * w.y;
        }
        float ox = fmaxf(gd.x * dx + bd.x, 0.f) + hd.x;
        float oy = fmaxf(gd.y * dy + bd.y, 0.f) + hd.y;
        hout[(size_t)node * 40 + t] = pack2(ox, oy);
        __syncthreads();
    }
}

// ---------------- MFMA head: oe + gates + sub/ctx; atomic-light pooling ----------------
// block = 256 = 4 waves; wave owns a 16-node tile. grid = NC/64 = 6250.
// ctx values -> ctxv (bf16 packed, plain stores); subp via in-wave 2-segment reduce.
__global__ __launch_bounds__(256) void k_headm(
    const unsigned* __restrict__ h2u, const int* __restrict__ hop,
    const int* __restrict__ mapper, const float* __restrict__ gall,
    const float* __restrict__ oe_w, const float* __restrict__ oe_b,
    const float* __restrict__ sub_w, const float* __restrict__ sub_b,
    const float* __restrict__ sub_g, const float* __restrict__ sub_bt,
    const float* __restrict__ ctx_w, const float* __restrict__ ctx_b,
    const float* __restrict__ ctx_g, const float* __restrict__ ctx_bt,
    float* __restrict__ cent, float* __restrict__ subp, unsigned* __restrict__ ctxv)
{
    __shared__ unsigned sOE[4 * 16 * 48];   // 12 KB
    __shared__ unsigned sSB[4 * 16 * 40];   // 10 KB
    __shared__ unsigned sCX[4 * 16 * 40];   // 10 KB
    __shared__ float    sT[4][16 * 68];     // 17 KB  D->A transpose buffer
    int tid = threadIdx.x;
    for (int i = tid; i < 4 * 16 * 48; i += 256) {
        int t = i / (16 * 48), r2 = i % (16 * 48), cc = r2 / 48, kp = r2 % 48;
        int col = 16 * t + cc;
        sOE[i] = (kp < 40) ? pack2(oe_w[(2 * kp) * 64 + col], oe_w[(2 * kp + 1) * 64 + col]) : 0u;
    }
    for (int i = tid; i < 4 * 16 * 40; i += 256) {
        int t = i / (16 * 40), r2 = i % (16 * 40), cc = r2 / 40, kp = r2 % 40;
        int col = 16 * t + cc;
        bool ok = kp < 32;
        sSB[i] = ok ? pack2(sub_w[(2 * kp) * 64 + col], sub_w[(2 * kp + 1) * 64 + col]) : 0u;
        sCX[i] = ok ? pack2(ctx_w[(2 * kp) * 64 + col], ctx_w[(2 * kp + 1) * 64 + col]) : 0u;
    }
    __syncthreads();

    int w = tid >> 6;
    int lane = tid & 63;
    int q = lane >> 4;        // 0..3
    int c = lane & 15;        // 0..15
    int base = (blockIdx.x * 4 + w) * 16;

    // ---- A fragments: h2 rows (row = c), K=80 in 3 steps (last zero-padded) ----
    const uint4* hrow = (const uint4*)(h2u + (size_t)(base + c) * 40);
    FragU a0, a1, a2;
    a0.u = hrow[q];
    a1.u = hrow[4 + q];
    a2.u = make_uint4(0u, 0u, 0u, 0u);
    if (q < 2) a2.u = hrow[8 + q];

    // ---- comb = h2 @ oe_w  (12 MFMA) ----
    f32x4 acc[4];
    #pragma unroll
    for (int t = 0; t < 4; t++) {
        const unsigned* pb = sOE + (t * 16 + c) * 48 + 4 * q;
        FragU b0, b1, b2;
        b0.u = *(const uint4*)(pb);
        b1.u = *(const uint4*)(pb + 16);
        b2.u = *(const uint4*)(pb + 32);
        f32x4 z = {0.f, 0.f, 0.f, 0.f};
        acc[t] = __builtin_amdgcn_mfma_f32_16x16x32_bf16(a0.b, b0.b, z, 0, 0, 0);
        acc[t] = __builtin_amdgcn_mfma_f32_16x16x32_bf16(a1.b, b1.b, acc[t], 0, 0, 0);
        acc[t] = __builtin_amdgcn_mfma_f32_16x16x32_bf16(a2.b, b2.b, acc[t], 0, 0, 0);
    }

    // ---- per-row metadata (rows 4q+reg) ----
    int mm[4], hn[4];
    #pragma unroll
    for (int r = 0; r < 4; r++) {
        int node = base + 4 * q + r;
        mm[r] = mapper[node];
        hn[r] = hop[node] + 1;
    }
    int sgA = base / S_;
    int k0 = (sgA + 1) * S_ - base;   // rows < k0 belong to sgA; rest to sgA+1
    if (k0 > 16) k0 = 16;

    // ---- bias, centroid store, write comb to transpose buffer ----
    #pragma unroll
    for (int t = 0; t < 4; t++) {
        int col = 16 * t + c;
        float ob = oe_b[col];
        #pragma unroll
        for (int r = 0; r < 4; r++) {
            int row = 4 * q + r;
            float v = acc[t][r] + ob;
            sT[w][row * 68 + col] = v;
            int sg = (row < k0) ? sgA : sgA + 1;
            if (mm[r] == sg) {
                cent[(size_t)sg * 64 + col] = v * gall[hn[r] * 64 + col];
            }
        }
    }

    // ---- read back as A' fragments, cvt to bf16 ----
    const float* trp = &sT[w][c * 68 + 8 * q];
    float4 v0 = *(const float4*)(trp);
    float4 v1 = *(const float4*)(trp + 4);
    float4 v2 = *(const float4*)(trp + 32);
    float4 v3 = *(const float4*)(trp + 36);
    FragU ap0, ap1;
    ap0.u = make_uint4(pack2(v0.x, v0.y), pack2(v0.z, v0.w), pack2(v1.x, v1.y), pack2(v1.z, v1.w));
    ap1.u = make_uint4(pack2(v2.x, v2.y), pack2(v2.z, v2.w), pack2(v3.x, v3.y), pack2(v3.z, v3.w));

    // ---- sub/ctx GEMMs (16 MFMA) ----
    f32x4 sa[4], ca[4];
    #pragma unroll
    for (int t = 0; t < 4; t++) {
        const unsigned* ps = sSB + (t * 16 + c) * 40 + 4 * q;
        const unsigned* pc = sCX + (t * 16 + c) * 40 + 4 * q;
        FragU b0, b1, d0, d1;
        b0.u = *(const uint4*)(ps);
        b1.u = *(const uint4*)(ps + 16);
        d0.u = *(const uint4*)(pc);
        d1.u = *(const uint4*)(pc + 16);
        f32x4 z = {0.f, 0.f, 0.f, 0.f};
        sa[t] = __builtin_amdgcn_mfma_f32_16x16x32_bf16(ap0.b, b0.b, z, 0, 0, 0);
        sa[t] = __builtin_amdgcn_mfma_f32_16x16x32_bf16(ap1.b, b1.b, sa[t], 0, 0, 0);
        ca[t] = __builtin_amdgcn_mfma_f32_16x16x32_bf16(ap0.b, d0.b, z, 0, 0, 0);
        ca[t] = __builtin_amdgcn_mfma_f32_16x16x32_bf16(ap1.b, d1.b, ca[t], 0, 0, 0);
    }

    // ---- epilogue ----
    #pragma unroll
    for (int t = 0; t < 4; t++) {
        int col = 16 * t + c;
        float sb = sub_b[col], sgm = sub_g[col], sbt = sub_bt[col];
        float cb = ctx_b[col], cgm = ctx_g[col], cbt = ctx_bt[col];
        float sA = 0.f, sB = 0.f;
        #pragma unroll
        for (int r = 0; r < 4; r++) {
            int row = 4 * q + r;
            float sval = fmaxf(sgm * (sa[t][r] + sb) + sbt, 0.f) * gall[(20 + hn[r]) * 64 + col];
            float cval = fmaxf(cgm * (ca[t][r] + cb) + cbt, 0.f) * gall[(40 + hn[r]) * 64 + col];
            // ctx: pack adjacent-lane pairs, plain store (no atomic)
            float partner = __shfl_xor(cval, 1);
            if ((c & 1) == 0) {
                ctxv[(size_t)(base + row) * 32 + (col >> 1)] = pack2(cval, partner);
            }
            if (row < k0) sA += sval; else sB += sval;
        }
        // sub: in-wave reduce over rows (q groups), <=2 subgraphs per tile
        sA += __shfl_xor(sA, 16); sA += __shfl_xor(sA, 32);
        sB += __shfl_xor(sB, 16); sB += __shfl_xor(sB, 32);
        if (q == 0) {
            atomicAdd(&subp[(size_t)sgA * 64 + col], sA);
            if (k0 < 16) atomicAdd(&subp[(size_t)(sgA + 1) * 64 + col], sB);
        }
    }
}

// ---------------- ctx pool: gather ctxv rows by node-CSR ----------------
__global__ __launch_bounds__(256) void k_ctxpool(
    const unsigned* __restrict__ ctxv, const int* __restrict__ nstart,
    const int* __restrict__ nidx, float* __restrict__ ctxp)
{
    int w = threadIdx.x >> 6, d = threadIdx.x & 63;
    int n = blockIdx.x * 4 + w;
    if (n >= N_) return;
    int s0 = nstart[n], s1 = nstart[n + 1];
    float acc = 0.f;
    for (int i = s0; i < s1; i++) {
        int row = nidx[i];
        float2 f = bf2f(ctxv[(size_t)row * 32 + (d >> 1)]);
        acc += (d & 1) ? f.y : f.x;
    }
    ctxp[(size_t)n * 64 + d] = acc;
}

// ---------------- final: combine pools + out_encoder ----------------
__global__ __launch_bounds__(256) void k_final(
    const float* __restrict__ cent, const float* __restrict__ subp, const float* __restrict__ ctxp,
    const int* __restrict__ nstart,
    const float* __restrict__ fo_w, const float* __restrict__ fo_b,
    const float* __restrict__ fo_g, const float* __restrict__ fo_bt,
    float* __restrict__ out)
{
    __shared__ float sW[64 * 64];
    int tid = threadIdx.x;
    for (int i = tid; i < 4096; i += 256) sW[i] = fo_w[i];
    int d = tid & 63, grp = tid >> 6;
    float rb = fo_b[d], rg = fo_g[d], rbt = fo_bt[d];
    __syncthreads();
    for (int n = blockIdx.x * 4 + grp; n < N_; n += gridDim.x * 4) {
        float cm = (float)max(nstart[n + 1] - nstart[n], 1);
        size_t o = (size_t)n * 64 + d;
        float r = cent[o] + subp[o] * (1.f / 20.f) + ctxp[o] / cm;
        float dot = rb;
        #pragma unroll 8
        for (int k = 0; k < 64; k++) dot += __shfl(r, k) * sW[k * 64 + d];
        out[o] = rg * dot + rbt;
    }
}

// ---------------- launch ----------------
extern "C" void kernel_launch(void* const* d_in, const int* in_sizes, int n_in,
                              void* d_out, int out_size, void* d_ws, size_t ws_size,
                              hipStream_t stream) {
    const float* x         = (const float*)d_in[0];
    const float* edge_attr = (const float*)d_in[1];
    const float* hop_table = (const float*)d_in[2];
    const float* conv_w1   = (const float*)d_in[3];
    const float* bn1_g     = (const float*)d_in[4];
    const float* bn1_b     = (const float*)d_in[5];
    const float* conv_w2   = (const float*)d_in[6];
    const float* bn2_g     = (const float*)d_in[7];
    const float* bn2_b     = (const float*)d_in[8];
    const float* oe_w      = (const float*)d_in[9];
    const float* oe_b      = (const float*)d_in[10];
    const float* sub_w     = (const float*)d_in[11];
    const float* sub_b     = (const float*)d_in[12];
    const float* sub_g     = (const float*)d_in[13];
    const float* sub_bt    = (const float*)d_in[14];
    const float* ctx_w     = (const float*)d_in[15];
    const float* ctx_b     = (const float*)d_in[16];
    const float* ctx_g     = (const float*)d_in[17];
    const float* ctx_bt    = (const float*)d_in[18];
    const float* gc_w      = (const float*)d_in[19];
    const float* gc_b      = (const float*)d_in[20];
    const float* gs_w      = (const float*)d_in[21];
    const float* gs_b      = (const float*)d_in[22];
    const float* gx_w      = (const float*)d_in[23];
    const float* gx_b      = (const float*)d_in[24];
    const float* fo_w      = (const float*)d_in[25];
    const float* fo_b      = (const float*)d_in[26];
    const float* fo_g      = (const float*)d_in[27];
    const float* fo_bt     = (const float*)d_in[28];
    const int* nodes_mapper  = (const int*)d_in[29];
    const int* edges_mapper  = (const int*)d_in[30];
    const int* edge_index    = (const int*)d_in[31];
    const int* batch         = (const int*)d_in[32];
    const int* hop_indicator = (const int*)d_in[33];
    (void)batch;
    float* out = (float*)d_out;

    // workspace bump allocator (256B aligned) — base layout ~165 MB (proven safe),
    // + optional 32 MB ea16 if ws_size allows.
    size_t off = 0;
    auto alloc = [&](size_t bytes) -> char* {
        char* p = (char*)d_ws + off;
        off = (off + bytes + 255) & ~(size_t)255;
        return p;
    };
    unsigned* hbuf0 = (unsigned*)alloc((size_t)NC_ * 40 * 4);  // 64 MB (bf16 pairs)
    unsigned* hbuf1 = (unsigned*)alloc((size_t)NC_ * 40 * 4);  // 64 MB; reused as ctxv after layer2
    int*   start    = (int*)alloc((size_t)(NC_ + 1) * 4);
    int*   cursor   = (int*)alloc((size_t)NC_ * 4);
    int*   bsums    = (int*)alloc(2048 * 4);
    int2*  e2       = (int2*)alloc((size_t)EC_ * 8);           // 16 MB
    float* cent     = (float*)alloc((size_t)N_ * 64 * 4);      // 5.12 MB
    float* subp     = (float*)alloc((size_t)N_ * 64 * 4);
    float* ctxp     = (float*)alloc((size_t)N_ * 64 * 4);
    int*   nstart   = (int*)alloc((size_t)(N_ + 1) * 4);
    int*   cursor_n = (int*)alloc((size_t)N_ * 4);
    int*   bsums_n  = (int*)alloc(256 * 4);
    int*   nidx     = (int*)alloc((size_t)NC_ * 4);            // 1.6 MB
    float* gall     = (float*)alloc((size_t)60 * 64 * 4);
    size_t ea16_bytes = (size_t)EB_ * 40 * 4;                  // 32 MB
    bool use_ea16 = (off + ea16_bytes + 256) <= ws_size;
    unsigned* eab = use_ea16 ? (unsigned*)alloc(ea16_bytes) : nullptr;
    unsigned* ctxv = hbuf1;   // alias: free after second k_gine
    (void)in_sizes; (void)n_in; (void)out_size;

    // zero what accumulates via atomics
    hipMemsetAsync(cursor, 0, (size_t)NC_ * 4, stream);
    hipMemsetAsync(cursor_n, 0, (size_t)N_ * 4, stream);
    hipMemsetAsync(subp, 0, (size_t)N_ * 64 * 4, stream);

    // h0 + gate table + optional bf16 edge_attr
    k_build_h0<<<(NC_ * 40 + 255) / 256, 256, 0, stream>>>(hbuf0, x, hop_table,
                                                           nodes_mapper, hop_indicator);
    k_gates<<<20, 64, 0, stream>>>(hop_table, gc_w, gc_b, gs_w, gs_b, gx_w, gx_b, gall);
    if (use_ea16)
        k_ea16<<<(EB_ * 40 + 255) / 256, 256, 0, stream>>>(eab, edge_attr);

    // edge CSR
    k_degree<<<(EC_ + 255) / 256, 256, 0, stream>>>(edge_index, cursor);
    k_bsum<<<NB_, 256, 0, stream>>>(cursor, bsums, NC_);
    k_scan_bsums<<<1, 256, 0, stream>>>(bsums, NB_);
    k_scan_apply<<<NB_, 256, 0, stream>>>(cursor, start, bsums, NC_, EC_);
    k_fill<<<(EC_ + 255) / 256, 256, 0, stream>>>(edge_index, edges_mapper, cursor, e2);

    // node CSR (counting sort by nodes_mapper)
    k_hist<<<(NC_ + 255) / 256, 256, 0, stream>>>(nodes_mapper, cursor_n);
    k_bsum<<<NBN_, 256, 0, stream>>>(cursor_n, bsums_n, N_);
    k_scan_bsums<<<1, 256, 0, stream>>>(bsums_n, NBN_);
    k_scan_apply<<<NBN_, 256, 0, stream>>>(cursor_n, nstart, bsums_n, N_, NC_);
    k_fill_nodes<<<(NC_ + 255) / 256, 256, 0, stream>>>(nodes_mapper, cursor_n, nidx);

    // two GINE layers (bf16 h)
    if (use_ea16) {
        k_gine<true><<<2048, 320, 0, stream>>>(hbuf0, hbuf1, edge_attr, eab, start, e2,
                                               conv_w1, bn1_g, bn1_b);
        k_gine<true><<<2048, 320, 0, stream>>>(hbuf1, hbuf0, edge_attr, eab, start, e2,
                                               conv_w2, bn2_g, bn2_b);
    } else {
        k_gine<false><<<2048, 320, 0, stream>>>(hbuf0, hbuf1, edge_attr, nullptr, start, e2,
                                                conv_w1, bn1_g, bn1_b);
        k_gine<false><<<2048, 320, 0, stream>>>(hbuf1, hbuf0, edge_attr, nullptr, start, e2,
                                                conv_w2, bn2_g, bn2_b);
    }

    // MFMA head (writes ctxv into hbuf1, subp via reduced atomics, cent plain)
    k_headm<<<NC_ / 64, 256, 0, stream>>>(hbuf0, hop_indicator, nodes_mapper, gall,
                                          oe_w, oe_b, sub_w, sub_b, sub_g, sub_bt,
                                          ctx_w, ctx_b, ctx_g, ctx_bt,
                                          cent, subp, ctxv);

    // ctx pool via node-CSR gather (atomic-free)
    k_ctxpool<<<N_ / 4, 256, 0, stream>>>(ctxv, nstart, nidx, ctxp);

    // final combine + out encoder
    k_final<<<1280, 256, 0, stream>>>(cent, subp, ctxp, nstart, fo_w, fo_b, fo_g, fo_bt, out);
}

// Round 7
// 1202.484 us; speedup vs baseline: 6.4452x; 1.1116x over previous
//
#include <hip/hip_runtime.h>
#include <hip/hip_bf16.h>

#define N_    20000
#define S_    20
#define NC_   400000
#define EC_   2000000
#define EB_   200000
#define NIN_  64
#define HOP_  16
#define D_    80
#define NOUT_ 64
#define NB_   1563   // ceil(NC/256)
#define NBN_  79     // ceil(N/256)

typedef __attribute__((ext_vector_type(8))) short bf16x8;
typedef __attribute__((ext_vector_type(4))) float f32x4;
union FragU { uint4 u; bf16x8 b; };

// ---------------- bf16 pack/unpack (pair layout: lo=feat 2p, hi=feat 2p+1) ----------------
__device__ __forceinline__ float2 bf2f(unsigned u) {
    float2 r;
    r.x = __uint_as_float(u << 16);
    r.y = __uint_as_float(u & 0xffff0000u);
    return r;
}
__device__ __forceinline__ unsigned f2bf_rne(float f) {
    unsigned u = __float_as_uint(f);
    return (u + 0x7fffu + ((u >> 16) & 1u)) >> 16;
}
__device__ __forceinline__ unsigned pack2(float a, float b) {
    return f2bf_rne(a) | (f2bf_rne(b) << 16);
}
__device__ __forceinline__ unsigned addpk(unsigned a, unsigned b) {
    float2 fa = bf2f(a), fb = bf2f(b);
    return pack2(fa.x + fb.x, fa.y + fb.y);
}
__device__ __forceinline__ uint4 addpk4(uint4 A, uint4 B) {
    return make_uint4(addpk(A.x, B.x), addpk(A.y, B.y), addpk(A.z, B.z), addpk(A.w, B.w));
}

// ---------------- scan utility (block of 256 = 4 waves) ----------------
__device__ __forceinline__ int blockExclScan(int v, int tid, int* lds, int* total) {
    int lane = tid & 63;
    int w = tid >> 6;
    int x = v;
    #pragma unroll
    for (int off = 1; off < 64; off <<= 1) {
        int y = __shfl_up(x, off, 64);
        if (lane >= off) x += y;
    }
    if (lane == 63) lds[w] = x;
    __syncthreads();
    if (tid == 0) {
        int acc = 0;
        #pragma unroll
        for (int i = 0; i < 4; i++) { int t = lds[i]; lds[4 + i] = acc; acc += t; }
        lds[8] = acc;
    }
    __syncthreads();
    int res = x - v + lds[4 + w];
    *total = lds[8];
    return res;
}

// ---------------- CSR build ----------------
__global__ __launch_bounds__(256) void k_degree(const int* __restrict__ eidx, int* __restrict__ deg) {
    int e = blockIdx.x * 256 + threadIdx.x;
    if (e >= EC_) return;
    atomicAdd(&deg[eidx[EC_ + e]], 1);
}

__global__ __launch_bounds__(256) void k_hist(const int* __restrict__ mapper, int* __restrict__ cnt) {
    int i = blockIdx.x * 256 + threadIdx.x;
    if (i >= NC_) return;
    atomicAdd(&cnt[mapper[i]], 1);
}

__global__ __launch_bounds__(256) void k_bsum(const int* __restrict__ deg, int* __restrict__ bsums, int n) {
    __shared__ int lds[9];
    int i = blockIdx.x * 256 + threadIdx.x;
    int v = (i < n) ? deg[i] : 0;
    int tot;
    blockExclScan(v, threadIdx.x, lds, &tot);
    if (threadIdx.x == 0) bsums[blockIdx.x] = tot;
}

__global__ __launch_bounds__(256) void k_scan_bsums(int* __restrict__ bsums, int nb) {
    __shared__ int lds[9];
    int carry = 0;
    for (int base = 0; base < nb; base += 256) {
        int i = base + threadIdx.x;
        int v = (i < nb) ? bsums[i] : 0;
        int tot;
        int ex = blockExclScan(v, threadIdx.x, lds, &tot);
        if (i < nb) bsums[i] = ex + carry;
        carry += tot;
        __syncthreads();
    }
}

__global__ __launch_bounds__(256) void k_scan_apply(
    int* __restrict__ cursor, int* __restrict__ start, const int* __restrict__ bsums,
    int n, int total)
{
    __shared__ int lds[9];
    int i = blockIdx.x * 256 + threadIdx.x;
    int v = (i < n) ? cursor[i] : 0;
    int tot;
    int ex = blockExclScan(v, threadIdx.x, lds, &tot);
    if (i < n) {
        int s = ex + bsums[blockIdx.x];
        start[i] = s;
        cursor[i] = s;
    }
    if (blockIdx.x == 0 && threadIdx.x == 0) start[n] = total;
}

// e2[pos] = {src, emap*32 + (hop[src]+1)}
__global__ __launch_bounds__(256) void k_fill(
    const int* __restrict__ eidx, const int* __restrict__ emap,
    const int* __restrict__ hop,
    int* __restrict__ cursor, int2* __restrict__ e2)
{
    int e = blockIdx.x * 256 + threadIdx.x;
    if (e >= EC_) return;
    int src = eidx[e];
    int dst = eidx[EC_ + e];
    int pk = emap[e] * 32 + (hop[src] + 1);
    int pos = atomicAdd(&cursor[dst], 1);
    e2[pos] = make_int2(src, pk);
}

__global__ __launch_bounds__(256) void k_fill_nodes(
    const int* __restrict__ mapper, int* __restrict__ cursor, int* __restrict__ nidx)
{
    int i = blockIdx.x * 256 + threadIdx.x;
    if (i >= NC_) return;
    int pos = atomicAdd(&cursor[mapper[i]], 1);
    nidx[pos] = i;
}

// ---------------- small tables: x -> bf16 pairs (2.5 MB), hop_table -> bf16 pairs ----------------
__global__ __launch_bounds__(256) void k_xb16(unsigned* __restrict__ xb, const float* __restrict__ x) {
    int idx = blockIdx.x * 256 + threadIdx.x;   // N*32
    if (idx >= N_ * 32) return;
    int row = idx >> 5, p = idx & 31;
    float2 v = *(const float2*)(x + (size_t)row * 64 + 2 * p);
    xb[idx] = pack2(v.x, v.y);
}
__global__ __launch_bounds__(160) void k_htb16(unsigned* __restrict__ htb, const float* __restrict__ ht) {
    int idx = threadIdx.x;                      // 20*8
    int row = idx >> 3, p = idx & 7;
    float2 v = *(const float2*)(ht + (size_t)row * 16 + 2 * p);
    htb[idx] = pack2(v.x, v.y);
}

// ---------------- edge_attr -> bf16 pairs ----------------
__global__ __launch_bounds__(256) void k_ea16(
    unsigned* __restrict__ eab, const float* __restrict__ ea)
{
    int idx = blockIdx.x * 256 + threadIdx.x;   // EB*40 pair-slots
    if (idx >= EB_ * 40) return;
    int row = idx / 40, t = idx - row * 40;
    float2 v = *(const float2*)(ea + (size_t)row * 80 + 2 * t);
    eab[idx] = pack2(v.x, v.y);
}

// ---------------- precompute hop gates: gall[{gc,gs,gx} x 20 x 64] ----------------
__global__ __launch_bounds__(64) void k_gates(
    const float* __restrict__ ht,
    const float* __restrict__ gc_w, const float* __restrict__ gc_b,
    const float* __restrict__ gs_w, const float* __restrict__ gs_b,
    const float* __restrict__ gx_w, const float* __restrict__ gx_b,
    float* __restrict__ gall)
{
    int h = blockIdx.x;        // 0..19
    int d = threadIdx.x;       // 0..63
    const float* htr = ht + h * 16;
    float a = gc_b[d], b = gs_b[d], c = gx_b[d];
    #pragma unroll
    for (int k = 0; k < 16; k++) {
        float hk = htr[k];
        a += hk * gc_w[k * 64 + d];
        b += hk * gs_w[k * 64 + d];
        c += hk * gx_w[k * 64 + d];
    }
    gall[h * 64 + d]            = 1.f / (1.f + __expf(-a));
    gall[(20 + h) * 64 + d]     = 1.f / (1.f + __expf(-b));
    gall[(40 + h) * 64 + d]     = 1.f / (1.f + __expf(-c));
}

// ---------------- edge aggregation: agg[node] = sum_e relu(h[src]+ea) (bf16 out) ----------------
// block = 320 = 8 groups x 40 threads; no LDS, no syncthreads.
// L==1: h[src] = concat(xb[mapper[src]], htb[hop[src]+1]) — small L2-resident tables.
template<int L, bool EA16>
__global__ __launch_bounds__(320) void k_agg(
    const unsigned* __restrict__ hin, const unsigned* __restrict__ xb,
    const unsigned* __restrict__ htb, const int* __restrict__ mapper,
    const unsigned* __restrict__ eab, const float* __restrict__ eaf,
    const int* __restrict__ start, const int2* __restrict__ e2,
    unsigned* __restrict__ agg)
{
    int tid = threadIdx.x;
    int grp = tid / 40;
    int p = tid - grp * 40;
    int node = blockIdx.x * 8 + grp;
    float ax = 0.f, ay = 0.f;
    int e = start[node], s1 = start[node + 1];

    auto hload = [&](int src, int pk) -> float2 {
        if (L == 1) {
            if (p < 32) {
                int xs = mapper[src];
                return bf2f(xb[(size_t)xs * 32 + p]);
            } else {
                return bf2f(htb[(pk & 31) * 8 + (p - 32)]);
            }
        } else {
            return bf2f(hin[(size_t)src * 40 + p]);
        }
    };
    auto eload = [&](int pk) -> float2 {
        int em = pk >> 5;
        if (EA16) return bf2f(eab[(size_t)em * 40 + p]);
        else      return *(const float2*)(eaf + (size_t)em * 80 + 2 * p);
    };

    for (; e + 4 <= s1; e += 4) {
        int2 d0 = e2[e], d1 = e2[e + 1], d2 = e2[e + 2], d3 = e2[e + 3];
        float2 h0 = hload(d0.x, d0.y), h1 = hload(d1.x, d1.y);
        float2 h2 = hload(d2.x, d2.y), h3 = hload(d3.x, d3.y);
        float2 q0 = eload(d0.y), q1 = eload(d1.y), q2 = eload(d2.y), q3 = eload(d3.y);
        ax += fmaxf(h0.x + q0.x, 0.f) + fmaxf(h1.x + q1.x, 0.f)
            + fmaxf(h2.x + q2.x, 0.f) + fmaxf(h3.x + q3.x, 0.f);
        ay += fmaxf(h0.y + q0.y, 0.f) + fmaxf(h1.y + q1.y, 0.f)
            + fmaxf(h2.y + q2.y, 0.f) + fmaxf(h3.y + q3.y, 0.f);
    }
    for (; e < s1; e++) {
        int2 d0 = e2[e];
        float2 h0 = hload(d0.x, d0.y);
        float2 q0 = eload(d0.y);
        ax += fmaxf(h0.x + q0.x, 0.f);
        ay += fmaxf(h0.y + q0.y, 0.f);
    }
    agg[(size_t)node * 40 + p] = pack2(ax, ay);
}

// ---------------- MFMA linear: out = relu(g*((h+agg)@W) + b) + h  (bf16 rows) ----------------
// block = 256 = 4 waves; wave owns 16 nodes. grid = NC/64.
// A: row=lane&15, k=8*(lane>>4)+j (3 K-steps, K=96 padded). B from LDS (stride-49 pad).
// D: col=lane&15 (+16t), row=4*(lane>>4)+reg.
template<int L>
__global__ __launch_bounds__(256) void k_lin(
    const unsigned* __restrict__ hbase, const unsigned* __restrict__ agg,
    unsigned* __restrict__ outp,
    const unsigned* __restrict__ xb, const unsigned* __restrict__ htb,
    const int* __restrict__ mapper, const int* __restrict__ hop,
    const float* __restrict__ W, const float* __restrict__ gv, const float* __restrict__ bv)
{
    __shared__ unsigned sWB[5 * 16 * 49];    // 15.7 KB, B-frags, pair-along-k, stride 49
    int tid = threadIdx.x;
    for (int i = tid; i < 5 * 16 * 49; i += 256) {
        int t = i / 784, r2 = i % 784, cc = r2 / 49, kp = r2 % 49;
        int col = 16 * t + cc;
        sWB[i] = (kp < 40) ? pack2(W[(2 * kp) * D_ + col], W[(2 * kp + 1) * D_ + col]) : 0u;
    }
    __syncthreads();

    int w = tid >> 6;
    int lane = tid & 63;
    int q = lane >> 4;
    int c = lane & 15;
    int base = (blockIdx.x * 4 + w) * 16;

    // ---- A = bf16(h + agg) ----
    const unsigned* ar = agg + (size_t)(base + c) * 40;
    uint4 g0 = *(const uint4*)(ar + 4 * q);
    uint4 g1 = *(const uint4*)(ar + 16 + 4 * q);
    uint4 g2 = (q < 2) ? *(const uint4*)(ar + 32 + 4 * q) : make_uint4(0u, 0u, 0u, 0u);
    uint4 h0v, h1v, h2v;
    if (L == 1) {
        int m = mapper[base + c];
        int hp = hop[base + c] + 1;
        const unsigned* xr = xb + (size_t)m * 32;
        h0v = *(const uint4*)(xr + 4 * q);
        h1v = *(const uint4*)(xr + 16 + 4 * q);
        h2v = (q < 2) ? *(const uint4*)(htb + hp * 8 + 4 * q) : make_uint4(0u, 0u, 0u, 0u);
    } else {
        const unsigned* hr = hbase + (size_t)(base + c) * 40;
        h0v = *(const uint4*)(hr + 4 * q);
        h1v = *(const uint4*)(hr + 16 + 4 * q);
        h2v = (q < 2) ? *(const uint4*)(hr + 32 + 4 * q) : make_uint4(0u, 0u, 0u, 0u);
    }
    FragU a0, a1, a2;
    a0.u = addpk4(h0v, g0);
    a1.u = addpk4(h1v, g1);
    a2.u = (q < 2) ? addpk4(h2v, g2) : make_uint4(0u, 0u, 0u, 0u);

    // ---- GEMM: 5 col-tiles x 3 K-steps = 15 MFMA ----
    f32x4 acc[5];
    #pragma unroll
    for (int t = 0; t < 5; t++) {
        const unsigned* pb = sWB + (t * 16 + c) * 49 + 4 * q;
        FragU b0, b1, b2;
        b0.u = *(const uint4*)(pb);
        b1.u = *(const uint4*)(pb + 16);
        b2.u = *(const uint4*)(pb + 32);
        f32x4 z = {0.f, 0.f, 0.f, 0.f};
        acc[t] = __builtin_amdgcn_mfma_f32_16x16x32_bf16(a0.b, b0.b, z, 0, 0, 0);
        acc[t] = __builtin_amdgcn_mfma_f32_16x16x32_bf16(a1.b, b1.b, acc[t], 0, 0, 0);
        acc[t] = __builtin_amdgcn_mfma_f32_16x16x32_bf16(a2.b, b2.b, acc[t], 0, 0, 0);
    }

    // ---- epilogue rows 4q+r: BN + ReLU + residual, pack-store ----
    int mm2[4], hp2[4];
    if (L == 1) {
        #pragma unroll
        for (int r = 0; r < 4; r++) {
            int row = base + 4 * q + r;
            mm2[r] = mapper[row];
            hp2[r] = hop[row] + 1;
        }
    }
    #pragma unroll
    for (int t = 0; t < 5; t++) {
        int col = 16 * t + c;
        float gc_ = gv[col], bc_ = bv[col];
        #pragma unroll
        for (int r = 0; r < 4; r++) {
            int row = base + 4 * q + r;
            unsigned hu;
            if (L == 1) {
                hu = (t < 4) ? xb[(size_t)mm2[r] * 32 + 8 * t + (c >> 1)]
                             : htb[hp2[r] * 8 + (c >> 1)];
            } else {
                hu = hbase[(size_t)row * 40 + 8 * t + (c >> 1)];
            }
            float2 hf = bf2f(hu);
            float hres = (c & 1) ? hf.y : hf.x;
            float o = fmaxf(gc_ * acc[t][r] + bc_, 0.f) + hres;
            float partner = __shfl_xor(o, 1);
            if (!(c & 1)) outp[(size_t)row * 40 + 8 * t + (c >> 1)] = pack2(o, partner);
        }
    }
}

// ---------------- MFMA head: oe + gates + sub/ctx; atomic-light pooling ----------------
__global__ __launch_bounds__(256) void k_headm(
    const unsigned* __restrict__ h2u, const int* __restrict__ hop,
    const int* __restrict__ mapper, const float* __restrict__ gall,
    const float* __restrict__ oe_w, const float* __restrict__ oe_b,
    const float* __restrict__ sub_w, const float* __restrict__ sub_b,
    const float* __restrict__ sub_g, const float* __restrict__ sub_bt,
    const float* __restrict__ ctx_w, const float* __restrict__ ctx_b,
    const float* __restrict__ ctx_g, const float* __restrict__ ctx_bt,
    float* __restrict__ cent, float* __restrict__ subp, unsigned* __restrict__ ctxv)
{
    __shared__ unsigned sOE[4 * 16 * 48];   // 12 KB
    __shared__ unsigned sSB[4 * 16 * 40];   // 10 KB
    __shared__ unsigned sCX[4 * 16 * 40];   // 10 KB
    __shared__ float    sT[4][16 * 68];     // 17 KB
    int tid = threadIdx.x;
    for (int i = tid; i < 4 * 16 * 48; i += 256) {
        int t = i / (16 * 48), r2 = i % (16 * 48), cc = r2 / 48, kp = r2 % 48;
        int col = 16 * t + cc;
        sOE[i] = (kp < 40) ? pack2(oe_w[(2 * kp) * 64 + col], oe_w[(2 * kp + 1) * 64 + col]) : 0u;
    }
    for (int i = tid; i < 4 * 16 * 40; i += 256) {
        int t = i / (16 * 40), r2 = i % (16 * 40), cc = r2 / 40, kp = r2 % 40;
        int col = 16 * t + cc;
        bool ok = kp < 32;
        sSB[i] = ok ? pack2(sub_w[(2 * kp) * 64 + col], sub_w[(2 * kp + 1) * 64 + col]) : 0u;
        sCX[i] = ok ? pack2(ctx_w[(2 * kp) * 64 + col], ctx_w[(2 * kp + 1) * 64 + col]) : 0u;
    }
    __syncthreads();

    int w = tid >> 6;
    int lane = tid & 63;
    int q = lane >> 4;
    int c = lane & 15;
    int base = (blockIdx.x * 4 + w) * 16;

    const uint4* hrow = (const uint4*)(h2u + (size_t)(base + c) * 40);
    FragU a0, a1, a2;
    a0.u = hrow[q];
    a1.u = hrow[4 + q];
    a2.u = make_uint4(0u, 0u, 0u, 0u);
    if (q < 2) a2.u = hrow[8 + q];

    f32x4 acc[4];
    #pragma unroll
    for (int t = 0; t < 4; t++) {
        const unsigned* pb = sOE + (t * 16 + c) * 48 + 4 * q;
        FragU b0, b1, b2;
        b0.u = *(const uint4*)(pb);
        b1.u = *(const uint4*)(pb + 16);
        b2.u = *(const uint4*)(pb + 32);
        f32x4 z = {0.f, 0.f, 0.f, 0.f};
        acc[t] = __builtin_amdgcn_mfma_f32_16x16x32_bf16(a0.b, b0.b, z, 0, 0, 0);
        acc[t] = __builtin_amdgcn_mfma_f32_16x16x32_bf16(a1.b, b1.b, acc[t], 0, 0, 0);
        acc[t] = __builtin_amdgcn_mfma_f32_16x16x32_bf16(a2.b, b2.b, acc[t], 0, 0, 0);
    }

    int mm[4], hn[4];
    #pragma unroll
    for (int r = 0; r < 4; r++) {
        int node = base + 4 * q + r;
        mm[r] = mapper[node];
        hn[r] = hop[node] + 1;
    }
    int sgA = base / S_;
    int k0 = (sgA + 1) * S_ - base;
    if (k0 > 16) k0 = 16;

    #pragma unroll
    for (int t = 0; t < 4; t++) {
        int col = 16 * t + c;
        float ob = oe_b[col];
        #pragma unroll
        for (int r = 0; r < 4; r++) {
            int row = 4 * q + r;
            float v = acc[t][r] + ob;
            sT[w][row * 68 + col] = v;
            int sg = (row < k0) ? sgA : sgA + 1;
            if (mm[r] == sg) {
                cent[(size_t)sg * 64 + col] = v * gall[hn[r] * 64 + col];
            }
        }
    }

    const float* trp = &sT[w][c * 68 + 8 * q];
    float4 v0 = *(const float4*)(trp);
    float4 v1 = *(const float4*)(trp + 4);
    float4 v2 = *(const float4*)(trp + 32);
    float4 v3 = *(const float4*)(trp + 36);
    FragU ap0, ap1;
    ap0.u = make_uint4(pack2(v0.x, v0.y), pack2(v0.z, v0.w), pack2(v1.x, v1.y), pack2(v1.z, v1.w));
    ap1.u = make_uint4(pack2(v2.x, v2.y), pack2(v2.z, v2.w), pack2(v3.x, v3.y), pack2(v3.z, v3.w));

    f32x4 sa[4], ca[4];
    #pragma unroll
    for (int t = 0; t < 4; t++) {
        const unsigned* ps = sSB + (t * 16 + c) * 40 + 4 * q;
        const unsigned* pc = sCX + (t * 16 + c) * 40 + 4 * q;
        FragU b0, b1, d0, d1;
        b0.u = *(const uint4*)(ps);
        b1.u = *(const uint4*)(ps + 16);
        d0.u = *(const uint4*)(pc);
        d1.u = *(const uint4*)(pc + 16);
        f32x4 z = {0.f, 0.f, 0.f, 0.f};
        sa[t] = __builtin_amdgcn_mfma_f32_16x16x32_bf16(ap0.b, b0.b, z, 0, 0, 0);
        sa[t] = __builtin_amdgcn_mfma_f32_16x16x32_bf16(ap1.b, b1.b, sa[t], 0, 0, 0);
        ca[t] = __builtin_amdgcn_mfma_f32_16x16x32_bf16(ap0.b, d0.b, z, 0, 0, 0);
        ca[t] = __builtin_amdgcn_mfma_f32_16x16x32_bf16(ap1.b, d1.b, ca[t], 0, 0, 0);
    }

    #pragma unroll
    for (int t = 0; t < 4; t++) {
        int col = 16 * t + c;
        float sb = sub_b[col], sgm = sub_g[col], sbt = sub_bt[col];
        float cb = ctx_b[col], cgm = ctx_g[col], cbt = ctx_bt[col];
        float sA = 0.f, sB = 0.f;
        #pragma unroll
        for (int r = 0; r < 4; r++) {
            int row = 4 * q + r;
            float sval = fmaxf(sgm * (sa[t][r] + sb) + sbt, 0.f) * gall[(20 + hn[r]) * 64 + col];
            float cval = fmaxf(cgm * (ca[t][r] + cb) + cbt, 0.f) * gall[(40 + hn[r]) * 64 + col];
            float partner = __shfl_xor(cval, 1);
            if ((c & 1) == 0) {
                ctxv[(size_t)(base + row) * 32 + (col >> 1)] = pack2(cval, partner);
            }
            if (row < k0) sA += sval; else sB += sval;
        }
        sA += __shfl_xor(sA, 16); sA += __shfl_xor(sA, 32);
        sB += __shfl_xor(sB, 16); sB += __shfl_xor(sB, 32);
        if (q == 0) {
            atomicAdd(&subp[(size_t)sgA * 64 + col], sA);
            if (k0 < 16) atomicAdd(&subp[(size_t)(sgA + 1) * 64 + col], sB);
        }
    }
}

// ---------------- ctx pool: gather ctxv rows by node-CSR (4-batched) ----------------
__global__ __launch_bounds__(256) void k_ctxpool(
    const unsigned* __restrict__ ctxv, const int* __restrict__ nstart,
    const int* __restrict__ nidx, float* __restrict__ ctxp)
{
    int w = threadIdx.x >> 6, d = threadIdx.x & 63;
    int n = blockIdx.x * 4 + w;
    if (n >= N_) return;
    int s0 = nstart[n], s1 = nstart[n + 1];
    int dh = d >> 1;
    float acc = 0.f;
    int i = s0;
    for (; i + 4 <= s1; i += 4) {
        int r0 = nidx[i], r1 = nidx[i + 1], r2 = nidx[i + 2], r3 = nidx[i + 3];
        float2 f0 = bf2f(ctxv[(size_t)r0 * 32 + dh]);
        float2 f1 = bf2f(ctxv[(size_t)r1 * 32 + dh]);
        float2 f2 = bf2f(ctxv[(size_t)r2 * 32 + dh]);
        float2 f3 = bf2f(ctxv[(size_t)r3 * 32 + dh]);
        acc += (d & 1) ? (f0.y + f1.y + f2.y + f3.y) : (f0.x + f1.x + f2.x + f3.x);
    }
    for (; i < s1; i++) {
        float2 f = bf2f(ctxv[(size_t)nidx[i] * 32 + dh]);
        acc += (d & 1) ? f.y : f.x;
    }
    ctxp[(size_t)n * 64 + d] = acc;
}

// ---------------- final: combine pools + out_encoder ----------------
__global__ __launch_bounds__(256) void k_final(
    const float* __restrict__ cent, const float* __restrict__ subp, const float* __restrict__ ctxp,
    const int* __restrict__ nstart,
    const float* __restrict__ fo_w, const float* __restrict__ fo_b,
    const float* __restrict__ fo_g, const float* __restrict__ fo_bt,
    float* __restrict__ out)
{
    __shared__ float sW[64 * 64];
    int tid = threadIdx.x;
    for (int i = tid; i < 4096; i += 256) sW[i] = fo_w[i];
    int d = tid & 63, grp = tid >> 6;
    float rb = fo_b[d], rg = fo_g[d], rbt = fo_bt[d];
    __syncthreads();
    for (int n = blockIdx.x * 4 + grp; n < N_; n += gridDim.x * 4) {
        float cm = (float)max(nstart[n + 1] - nstart[n], 1);
        size_t o = (size_t)n * 64 + d;
        float r = cent[o] + subp[o] * (1.f / 20.f) + ctxp[o] / cm;
        float dot = rb;
        #pragma unroll 8
        for (int k = 0; k < 64; k++) dot += __shfl(r, k) * sW[k * 64 + d];
        out[o] = rg * dot + rbt;
    }
}

// ---------------- launch ----------------
extern "C" void kernel_launch(void* const* d_in, const int* in_sizes, int n_in,
                              void* d_out, int out_size, void* d_ws, size_t ws_size,
                              hipStream_t stream) {
    const float* x         = (const float*)d_in[0];
    const float* edge_attr = (const float*)d_in[1];
    const float* hop_table = (const float*)d_in[2];
    const float* conv_w1   = (const float*)d_in[3];
    const float* bn1_g     = (const float*)d_in[4];
    const float* bn1_b     = (const float*)d_in[5];
    const float* conv_w2   = (const float*)d_in[6];
    const float* bn2_g     = (const float*)d_in[7];
    const float* bn2_b     = (const float*)d_in[8];
    const float* oe_w      = (const float*)d_in[9];
    const float* oe_b      = (const float*)d_in[10];
    const float* sub_w     = (const float*)d_in[11];
    const float* sub_b     = (const float*)d_in[12];
    const float* sub_g     = (const float*)d_in[13];
    const float* sub_bt    = (const float*)d_in[14];
    const float* ctx_w     = (const float*)d_in[15];
    const float* ctx_b     = (const float*)d_in[16];
    const float* ctx_g     = (const float*)d_in[17];
    const float* ctx_bt    = (const float*)d_in[18];
    const float* gc_w      = (const float*)d_in[19];
    const float* gc_b      = (const float*)d_in[20];
    const float* gs_w      = (const float*)d_in[21];
    const float* gs_b      = (const float*)d_in[22];
    const float* gx_w      = (const float*)d_in[23];
    const float* gx_b      = (const float*)d_in[24];
    const float* fo_w      = (const float*)d_in[25];
    const float* fo_b      = (const float*)d_in[26];
    const float* fo_g      = (const float*)d_in[27];
    const float* fo_bt     = (const float*)d_in[28];
    const int* nodes_mapper  = (const int*)d_in[29];
    const int* edges_mapper  = (const int*)d_in[30];
    const int* edge_index    = (const int*)d_in[31];
    const int* batch         = (const int*)d_in[32];
    const int* hop_indicator = (const int*)d_in[33];
    (void)batch;
    float* out = (float*)d_out;

    size_t off = 0;
    auto alloc = [&](size_t bytes) -> char* {
        char* p = (char*)d_ws + off;
        off = (off + bytes + 255) & ~(size_t)255;
        return p;
    };
    unsigned* hbuf0 = (unsigned*)alloc((size_t)NC_ * 40 * 4);  // 64 MB: agg1 -> agg2 -> h2 (in-place)
    unsigned* hbuf1 = (unsigned*)alloc((size_t)NC_ * 40 * 4);  // 64 MB: h1 -> ctxv
    int*   start    = (int*)alloc((size_t)(NC_ + 1) * 4);
    int*   cursor   = (int*)alloc((size_t)NC_ * 4);
    int*   bsums    = (int*)alloc(2048 * 4);
    int2*  e2       = (int2*)alloc((size_t)EC_ * 8);           // 16 MB
    float* cent     = (float*)alloc((size_t)N_ * 64 * 4);
    float* subp     = (float*)alloc((size_t)N_ * 64 * 4);
    float* ctxp     = (float*)alloc((size_t)N_ * 64 * 4);
    int*   nstart   = (int*)alloc((size_t)(N_ + 1) * 4);
    int*   cursor_n = (int*)alloc((size_t)N_ * 4);
    int*   bsums_n  = (int*)alloc(256 * 4);
    int*   nidx     = (int*)alloc((size_t)NC_ * 4);
    float* gall     = (float*)alloc((size_t)60 * 64 * 4);
    unsigned* xb    = (unsigned*)alloc((size_t)N_ * 32 * 4);   // 2.56 MB
    unsigned* htb   = (unsigned*)alloc((size_t)20 * 8 * 4);
    size_t ea16_bytes = (size_t)EB_ * 40 * 4;                  // 32 MB
    bool use_ea16 = (off + ea16_bytes + 256) <= ws_size;
    unsigned* eab = use_ea16 ? (unsigned*)alloc(ea16_bytes) : nullptr;
    unsigned* ctxv = hbuf1;
    (void)in_sizes; (void)n_in; (void)out_size;

    hipMemsetAsync(cursor, 0, (size_t)NC_ * 4, stream);
    hipMemsetAsync(cursor_n, 0, (size_t)N_ * 4, stream);
    hipMemsetAsync(subp, 0, (size_t)N_ * 64 * 4, stream);

    // tables
    k_xb16<<<(N_ * 32 + 255) / 256, 256, 0, stream>>>(xb, x);
    k_htb16<<<1, 160, 0, stream>>>(htb, hop_table);
    k_gates<<<20, 64, 0, stream>>>(hop_table, gc_w, gc_b, gs_w, gs_b, gx_w, gx_b, gall);
    if (use_ea16)
        k_ea16<<<(EB_ * 40 + 255) / 256, 256, 0, stream>>>(eab, edge_attr);

    // edge CSR (packed {src, emap*32+hop+1})
    k_degree<<<(EC_ + 255) / 256, 256, 0, stream>>>(edge_index, cursor);
    k_bsum<<<NB_, 256, 0, stream>>>(cursor, bsums, NC_);
    k_scan_bsums<<<1, 256, 0, stream>>>(bsums, NB_);
    k_scan_apply<<<NB_, 256, 0, stream>>>(cursor, start, bsums, NC_, EC_);
    k_fill<<<(EC_ + 255) / 256, 256, 0, stream>>>(edge_index, edges_mapper, hop_indicator,
                                                  cursor, e2);

    // node CSR (counting sort by nodes_mapper)
    k_hist<<<(NC_ + 255) / 256, 256, 0, stream>>>(nodes_mapper, cursor_n);
    k_bsum<<<NBN_, 256, 0, stream>>>(cursor_n, bsums_n, N_);
    k_scan_bsums<<<1, 256, 0, stream>>>(bsums_n, NBN_);
    k_scan_apply<<<NBN_, 256, 0, stream>>>(cursor_n, nstart, bsums_n, N_, NC_);
    k_fill_nodes<<<(NC_ + 255) / 256, 256, 0, stream>>>(nodes_mapper, cursor_n, nidx);

    // layer 1: agg (from xb/htb tables) -> hbuf0; lin -> hbuf1
    if (use_ea16)
        k_agg<1, true><<<NC_ / 8, 320, 0, stream>>>(nullptr, xb, htb, nodes_mapper,
                                                    eab, edge_attr, start, e2, hbuf0);
    else
        k_agg<1, false><<<NC_ / 8, 320, 0, stream>>>(nullptr, xb, htb, nodes_mapper,
                                                     eab, edge_attr, start, e2, hbuf0);
    k_lin<1><<<NC_ / 64, 256, 0, stream>>>(nullptr, hbuf0, hbuf1, xb, htb,
                                           nodes_mapper, hop_indicator,
                                           conv_w1, bn1_g, bn1_b);

    // layer 2: agg (from h1) -> hbuf0; lin in-place -> hbuf0
    if (use_ea16)
        k_agg<2, true><<<NC_ / 8, 320, 0, stream>>>(hbuf1, xb, htb, nodes_mapper,
                                                    eab, edge_attr, start, e2, hbuf0);
    else
        k_agg<2, false><<<NC_ / 8, 320, 0, stream>>>(hbuf1, xb, htb, nodes_mapper,
                                                     eab, edge_attr, start, e2, hbuf0);
    k_lin<2><<<NC_ / 64, 256, 0, stream>>>(hbuf1, hbuf0, hbuf0, xb, htb,
                                           nodes_mapper, hop_indicator,
                                           conv_w2, bn2_g, bn2_b);

    // MFMA head (h2 = hbuf0; ctxv aliases hbuf1)
    k_headm<<<NC_ / 64, 256, 0, stream>>>(hbuf0, hop_indicator, nodes_mapper, gall,
                                          oe_w, oe_b, sub_w, sub_b, sub_g, sub_bt,
                                          ctx_w, ctx_b, ctx_g, ctx_bt,
                                          cent, subp, ctxv);

    // ctx pool via node-CSR gather
    k_ctxpool<<<N_ / 4, 256, 0, stream>>>(ctxv, nstart, nidx, ctxp);

    // final combine + out encoder
    k_final<<<1280, 256, 0, stream>>>(cent, subp, ctxp, nstart, fo_w, fo_b, fo_g, fo_bt, out);
}

// Round 8
// 1117.770 us; speedup vs baseline: 6.9337x; 1.0758x over previous
//
#include <hip/hip_runtime.h>
#include <hip/hip_bf16.h>

#define N_    20000
#define S_    20
#define NC_   400000
#define EC_   2000000
#define EB_   200000
#define NIN_  64
#define HOP_  16
#define D_    80
#define NOUT_ 64
#define NB_   1563   // ceil(NC/256)
#define NBN_  79     // ceil(N/256)

typedef __attribute__((ext_vector_type(8))) short bf16x8;
typedef __attribute__((ext_vector_type(4))) float f32x4;
union FragU { uint4 u; bf16x8 b; };

// ---------------- bf16 pack/unpack (pair layout: lo=feat 2p, hi=feat 2p+1) ----------------
__device__ __forceinline__ float2 bf2f(unsigned u) {
    float2 r;
    r.x = __uint_as_float(u << 16);
    r.y = __uint_as_float(u & 0xffff0000u);
    return r;
}
__device__ __forceinline__ unsigned f2bf_rne(float f) {
    unsigned u = __float_as_uint(f);
    return (u + 0x7fffu + ((u >> 16) & 1u)) >> 16;
}
__device__ __forceinline__ unsigned pack2(float a, float b) {
    return f2bf_rne(a) | (f2bf_rne(b) << 16);
}

// accumulate relu(h+ea) for 4 bf16-pairs into A[0..7]
__device__ __forceinline__ void acc4(float* A, uint4 hv, uint4 ev) {
    const unsigned* hp = (const unsigned*)&hv;
    const unsigned* ep = (const unsigned*)&ev;
    #pragma unroll
    for (int j = 0; j < 4; j++) {
        float2 hs = bf2f(hp[j]);
        float2 eq = bf2f(ep[j]);
        A[2 * j]     += fmaxf(hs.x + eq.x, 0.f);
        A[2 * j + 1] += fmaxf(hs.y + eq.y, 0.f);
    }
}
__device__ __forceinline__ void acc4f(float* A, uint4 hv, const float* er, int off) {
    const unsigned* hp = (const unsigned*)&hv;
    #pragma unroll
    for (int j = 0; j < 4; j++) {
        float2 hs = bf2f(hp[j]);
        float2 eq = *(const float2*)(er + 2 * (off + j));
        A[2 * j]     += fmaxf(hs.x + eq.x, 0.f);
        A[2 * j + 1] += fmaxf(hs.y + eq.y, 0.f);
    }
}

// ---------------- scan utility (block of 256 = 4 waves) ----------------
__device__ __forceinline__ int blockExclScan(int v, int tid, int* lds, int* total) {
    int lane = tid & 63;
    int w = tid >> 6;
    int x = v;
    #pragma unroll
    for (int off = 1; off < 64; off <<= 1) {
        int y = __shfl_up(x, off, 64);
        if (lane >= off) x += y;
    }
    if (lane == 63) lds[w] = x;
    __syncthreads();
    if (tid == 0) {
        int acc = 0;
        #pragma unroll
        for (int i = 0; i < 4; i++) { int t = lds[i]; lds[4 + i] = acc; acc += t; }
        lds[8] = acc;
    }
    __syncthreads();
    int res = x - v + lds[4 + w];
    *total = lds[8];
    return res;
}

// ---------------- CSR build ----------------
__global__ __launch_bounds__(256) void k_degree(const int* __restrict__ eidx, int* __restrict__ deg) {
    int e = blockIdx.x * 256 + threadIdx.x;
    if (e >= EC_) return;
    atomicAdd(&deg[eidx[EC_ + e]], 1);
}

__global__ __launch_bounds__(256) void k_hist(const int* __restrict__ mapper, int* __restrict__ cnt) {
    int i = blockIdx.x * 256 + threadIdx.x;
    if (i >= NC_) return;
    atomicAdd(&cnt[mapper[i]], 1);
}

__global__ __launch_bounds__(256) void k_bsum(const int* __restrict__ deg, int* __restrict__ bsums, int n) {
    __shared__ int lds[9];
    int i = blockIdx.x * 256 + threadIdx.x;
    int v = (i < n) ? deg[i] : 0;
    int tot;
    blockExclScan(v, threadIdx.x, lds, &tot);
    if (threadIdx.x == 0) bsums[blockIdx.x] = tot;
}

__global__ __launch_bounds__(256) void k_scan_bsums(int* __restrict__ bsums, int nb) {
    __shared__ int lds[9];
    int carry = 0;
    for (int base = 0; base < nb; base += 256) {
        int i = base + threadIdx.x;
        int v = (i < nb) ? bsums[i] : 0;
        int tot;
        int ex = blockExclScan(v, threadIdx.x, lds, &tot);
        if (i < nb) bsums[i] = ex + carry;
        carry += tot;
        __syncthreads();
    }
}

__global__ __launch_bounds__(256) void k_scan_apply(
    int* __restrict__ cursor, int* __restrict__ start, const int* __restrict__ bsums,
    int n, int total)
{
    __shared__ int lds[9];
    int i = blockIdx.x * 256 + threadIdx.x;
    int v = (i < n) ? cursor[i] : 0;
    int tot;
    int ex = blockExclScan(v, threadIdx.x, lds, &tot);
    if (i < n) {
        int s = ex + bsums[blockIdx.x];
        start[i] = s;
        cursor[i] = s;
    }
    if (blockIdx.x == 0 && threadIdx.x == 0) start[n] = total;
}

// e2[pos] = {src, emap*32 + (hop[src]+1)}
__global__ __launch_bounds__(256) void k_fill(
    const int* __restrict__ eidx, const int* __restrict__ emap,
    const int* __restrict__ hop,
    int* __restrict__ cursor, int2* __restrict__ e2)
{
    int e = blockIdx.x * 256 + threadIdx.x;
    if (e >= EC_) return;
    int src = eidx[e];
    int dst = eidx[EC_ + e];
    int pk = emap[e] * 32 + (hop[src] + 1);
    int pos = atomicAdd(&cursor[dst], 1);
    e2[pos] = make_int2(src, pk);
}

__global__ __launch_bounds__(256) void k_fill_nodes(
    const int* __restrict__ mapper, int* __restrict__ cursor, int* __restrict__ nidx)
{
    int i = blockIdx.x * 256 + threadIdx.x;
    if (i >= NC_) return;
    int pos = atomicAdd(&cursor[mapper[i]], 1);
    nidx[pos] = i;
}

// ---------------- small tables: x -> bf16 pairs (2.5 MB), hop_table -> bf16 pairs ----------------
__global__ __launch_bounds__(256) void k_xb16(unsigned* __restrict__ xb, const float* __restrict__ x) {
    int idx = blockIdx.x * 256 + threadIdx.x;   // N*32
    if (idx >= N_ * 32) return;
    int row = idx >> 5, p = idx & 31;
    float2 v = *(const float2*)(x + (size_t)row * 64 + 2 * p);
    xb[idx] = pack2(v.x, v.y);
}
__global__ __launch_bounds__(160) void k_htb16(unsigned* __restrict__ htb, const float* __restrict__ ht) {
    int idx = threadIdx.x;                      // 20*8
    int row = idx >> 3, p = idx & 7;
    float2 v = *(const float2*)(ht + (size_t)row * 16 + 2 * p);
    htb[idx] = pack2(v.x, v.y);
}

// ---------------- edge_attr -> bf16 pairs ----------------
__global__ __launch_bounds__(256) void k_ea16(
    unsigned* __restrict__ eab, const float* __restrict__ ea)
{
    int idx = blockIdx.x * 256 + threadIdx.x;   // EB*40 pair-slots
    if (idx >= EB_ * 40) return;
    int row = idx / 40, t = idx - row * 40;
    float2 v = *(const float2*)(ea + (size_t)row * 80 + 2 * t);
    eab[idx] = pack2(v.x, v.y);
}

// ---------------- precompute hop gates: gall[{gc,gs,gx} x 20 x 64] ----------------
__global__ __launch_bounds__(64) void k_gates(
    const float* __restrict__ ht,
    const float* __restrict__ gc_w, const float* __restrict__ gc_b,
    const float* __restrict__ gs_w, const float* __restrict__ gs_b,
    const float* __restrict__ gx_w, const float* __restrict__ gx_b,
    float* __restrict__ gall)
{
    int h = blockIdx.x;        // 0..19
    int d = threadIdx.x;       // 0..63
    const float* htr = ht + h * 16;
    float a = gc_b[d], b = gs_b[d], c = gx_b[d];
    #pragma unroll
    for (int k = 0; k < 16; k++) {
        float hk = htr[k];
        a += hk * gc_w[k * 64 + d];
        b += hk * gs_w[k * 64 + d];
        c += hk * gx_w[k * 64 + d];
    }
    gall[h * 64 + d]            = 1.f / (1.f + __expf(-a));
    gall[(20 + h) * 64 + d]     = 1.f / (1.f + __expf(-b));
    gall[(40 + h) * 64 + d]     = 1.f / (1.f + __expf(-c));
}

// ---------------- fused GINE layer: edge-agg in A-fragment layout + MFMA + epilogue ----------------
// block = 256 = 4 waves; wave owns 16 nodes (c = lane&15), q = lane>>4 owns K-slices
// {4q, 16+4q, 32+4q(q<2)} (bf16 pairs). grid = NC/64.
template<int L, bool EA16>
__global__ __launch_bounds__(256) void k_gine_f(
    const unsigned* __restrict__ hin,
    const unsigned* __restrict__ xb, const unsigned* __restrict__ htb,
    const int* __restrict__ mapper, const int* __restrict__ hop,
    const unsigned* __restrict__ eab, const float* __restrict__ eaf,
    const int* __restrict__ start, const int2* __restrict__ e2,
    unsigned* __restrict__ outp,
    const float* __restrict__ W, const float* __restrict__ gv, const float* __restrict__ bv)
{
    __shared__ unsigned sWB[5 * 16 * 49];    // 15.7 KB, B-frags, pair-along-k, stride 49
    int tid = threadIdx.x;
    for (int i = tid; i < 5 * 16 * 49; i += 256) {
        int t = i / 784, r2 = i % 784, cc = r2 / 49, kp = r2 % 49;
        int col = 16 * t + cc;
        sWB[i] = (kp < 40) ? pack2(W[(2 * kp) * D_ + col], W[(2 * kp + 1) * D_ + col]) : 0u;
    }
    __syncthreads();

    int w = tid >> 6;
    int lane = tid & 63;
    int q = lane >> 4;
    int c = lane & 15;
    int base = (blockIdx.x * 4 + w) * 16;
    int node = base + c;
    int off0 = 4 * q, off1 = 16 + 4 * q, off2 = 32 + 4 * q;

    // ---- edge aggregation into f32 A-slices ----
    float A0[8] = {0.f, 0.f, 0.f, 0.f, 0.f, 0.f, 0.f, 0.f};
    float A1[8] = {0.f, 0.f, 0.f, 0.f, 0.f, 0.f, 0.f, 0.f};
    float A2[8] = {0.f, 0.f, 0.f, 0.f, 0.f, 0.f, 0.f, 0.f};
    uint4 zz = make_uint4(0u, 0u, 0u, 0u);

    int e = start[node];
    int s1 = start[node + 1];
    while (__any(e < s1)) {
        bool a0 = e < s1;
        bool a1 = (e + 1) < s1;
        int ee0 = max(min(e, s1 - 1), 0);
        int ee1 = max(min(e + 1, s1 - 1), 0);
        int2 ed0 = e2[ee0];
        int2 ed1 = e2[ee1];
        uint4 s00, s01, s02, s10, s11, s12;
        if (L == 1) {
            int m0 = mapper[ed0.x];
            int m1 = mapper[ed1.x];
            const unsigned* x0 = xb + (size_t)m0 * 32;
            const unsigned* x1 = xb + (size_t)m1 * 32;
            s00 = *(const uint4*)(x0 + off0);
            s01 = *(const uint4*)(x0 + off1);
            s02 = (q < 2) ? *(const uint4*)(htb + (ed0.y & 31) * 8 + off0) : zz;
            s10 = *(const uint4*)(x1 + off0);
            s11 = *(const uint4*)(x1 + off1);
            s12 = (q < 2) ? *(const uint4*)(htb + (ed1.y & 31) * 8 + off0) : zz;
        } else {
            const unsigned* h0 = hin + (size_t)ed0.x * 40;
            const unsigned* h1 = hin + (size_t)ed1.x * 40;
            s00 = *(const uint4*)(h0 + off0);
            s01 = *(const uint4*)(h0 + off1);
            s02 = (q < 2) ? *(const uint4*)(h0 + off2) : zz;
            s10 = *(const uint4*)(h1 + off0);
            s11 = *(const uint4*)(h1 + off1);
            s12 = (q < 2) ? *(const uint4*)(h1 + off2) : zz;
        }
        int em0 = ed0.y >> 5, em1 = ed1.y >> 5;
        if (EA16) {
            const unsigned* e0p = eab + (size_t)em0 * 40;
            const unsigned* e1p = eab + (size_t)em1 * 40;
            uint4 q00 = *(const uint4*)(e0p + off0);
            uint4 q01 = *(const uint4*)(e0p + off1);
            uint4 q02 = (q < 2) ? *(const uint4*)(e0p + off2) : zz;
            uint4 q10 = *(const uint4*)(e1p + off0);
            uint4 q11 = *(const uint4*)(e1p + off1);
            uint4 q12 = (q < 2) ? *(const uint4*)(e1p + off2) : zz;
            if (a0) { acc4(A0, s00, q00); acc4(A1, s01, q01); if (q < 2) acc4(A2, s02, q02); }
            if (a1) { acc4(A0, s10, q10); acc4(A1, s11, q11); if (q < 2) acc4(A2, s12, q12); }
        } else {
            const float* e0p = eaf + (size_t)em0 * 80;
            const float* e1p = eaf + (size_t)em1 * 80;
            if (a0) { acc4f(A0, s00, e0p, off0); acc4f(A1, s01, e0p, off1); if (q < 2) acc4f(A2, s02, e0p, off2); }
            if (a1) { acc4f(A0, s10, e1p, off0); acc4f(A1, s11, e1p, off1); if (q < 2) acc4f(A2, s12, e1p, off2); }
        }
        e += 2;
    }

    // ---- own h (A-slices) ----
    uint4 h0v, h1v, h2v;
    if (L == 1) {
        int m = mapper[node];
        int hp = hop[node] + 1;
        const unsigned* xr = xb + (size_t)m * 32;
        h0v = *(const uint4*)(xr + off0);
        h1v = *(const uint4*)(xr + off1);
        h2v = (q < 2) ? *(const uint4*)(htb + hp * 8 + off0) : zz;
    } else {
        const unsigned* hr = hin + (size_t)node * 40;
        h0v = *(const uint4*)(hr + off0);
        h1v = *(const uint4*)(hr + off1);
        h2v = (q < 2) ? *(const uint4*)(hr + off2) : zz;
    }

    // ---- A = bf16(h + agg) ----
    FragU a0F, a1F, a2F;
    {
        const unsigned* hp0 = (const unsigned*)&h0v;
        const unsigned* hp1 = (const unsigned*)&h1v;
        const unsigned* hp2 = (const unsigned*)&h2v;
        unsigned r0[4], r1[4], r2[4];
        #pragma unroll
        for (int j = 0; j < 4; j++) {
            float2 f0 = bf2f(hp0[j]);
            float2 f1 = bf2f(hp1[j]);
            float2 f2 = bf2f(hp2[j]);
            r0[j] = pack2(A0[2 * j] + f0.x, A0[2 * j + 1] + f0.y);
            r1[j] = pack2(A1[2 * j] + f1.x, A1[2 * j + 1] + f1.y);
            r2[j] = (q < 2) ? pack2(A2[2 * j] + f2.x, A2[2 * j + 1] + f2.y) : 0u;
        }
        a0F.u = make_uint4(r0[0], r0[1], r0[2], r0[3]);
        a1F.u = make_uint4(r1[0], r1[1], r1[2], r1[3]);
        a2F.u = make_uint4(r2[0], r2[1], r2[2], r2[3]);
    }

    // ---- GEMM: 5 col-tiles x 3 K-steps = 15 MFMA ----
    f32x4 acc[5];
    #pragma unroll
    for (int t = 0; t < 5; t++) {
        const unsigned* pb = sWB + (t * 16 + c) * 49 + 4 * q;
        FragU b0, b1, b2;
        b0.u = *(const uint4*)(pb);
        b1.u = *(const uint4*)(pb + 16);
        b2.u = *(const uint4*)(pb + 32);
        f32x4 z = {0.f, 0.f, 0.f, 0.f};
        acc[t] = __builtin_amdgcn_mfma_f32_16x16x32_bf16(a0F.b, b0.b, z, 0, 0, 0);
        acc[t] = __builtin_amdgcn_mfma_f32_16x16x32_bf16(a1F.b, b1.b, acc[t], 0, 0, 0);
        acc[t] = __builtin_amdgcn_mfma_f32_16x16x32_bf16(a2F.b, b2.b, acc[t], 0, 0, 0);
    }

    // ---- epilogue rows 4q+r: BN + ReLU + residual, pack-store ----
    int mm2[4], hp2v[4];
    if (L == 1) {
        #pragma unroll
        for (int r = 0; r < 4; r++) {
            int row = base + 4 * q + r;
            mm2[r] = mapper[row];
            hp2v[r] = hop[row] + 1;
        }
    }
    #pragma unroll
    for (int t = 0; t < 5; t++) {
        int col = 16 * t + c;
        float gc_ = gv[col], bc_ = bv[col];
        #pragma unroll
        for (int r = 0; r < 4; r++) {
            int row = base + 4 * q + r;
            unsigned hu;
            if (L == 1) {
                hu = (t < 4) ? xb[(size_t)mm2[r] * 32 + 8 * t + (c >> 1)]
                             : htb[hp2v[r] * 8 + (c >> 1)];
            } else {
                hu = hin[(size_t)row * 40 + 8 * t + (c >> 1)];
            }
            float2 hf = bf2f(hu);
            float hres = (c & 1) ? hf.y : hf.x;
            float o = fmaxf(gc_ * acc[t][r] + bc_, 0.f) + hres;
            float partner = __shfl_xor(o, 1);
            if (!(c & 1)) outp[(size_t)row * 40 + 8 * t + (c >> 1)] = pack2(o, partner);
        }
    }
}

// ---------------- MFMA head: oe + gates + sub/ctx; atomic-light pooling ----------------
__global__ __launch_bounds__(256) void k_headm(
    const unsigned* __restrict__ h2u, const int* __restrict__ hop,
    const int* __restrict__ mapper, const float* __restrict__ gall,
    const float* __restrict__ oe_w, const float* __restrict__ oe_b,
    const float* __restrict__ sub_w, const float* __restrict__ sub_b,
    const float* __restrict__ sub_g, const float* __restrict__ sub_bt,
    const float* __restrict__ ctx_w, const float* __restrict__ ctx_b,
    const float* __restrict__ ctx_g, const float* __restrict__ ctx_bt,
    float* __restrict__ cent, float* __restrict__ subp, unsigned* __restrict__ ctxv)
{
    __shared__ unsigned sOE[4 * 16 * 48];   // 12 KB
    __shared__ unsigned sSB[4 * 16 * 40];   // 10 KB
    __shared__ unsigned sCX[4 * 16 * 40];   // 10 KB
    __shared__ float    sT[4][16 * 68];     // 17 KB
    int tid = threadIdx.x;
    for (int i = tid; i < 4 * 16 * 48; i += 256) {
        int t = i / (16 * 48), r2 = i % (16 * 48), cc = r2 / 48, kp = r2 % 48;
        int col = 16 * t + cc;
        sOE[i] = (kp < 40) ? pack2(oe_w[(2 * kp) * 64 + col], oe_w[(2 * kp + 1) * 64 + col]) : 0u;
    }
    for (int i = tid; i < 4 * 16 * 40; i += 256) {
        int t = i / (16 * 40), r2 = i % (16 * 40), cc = r2 / 40, kp = r2 % 40;
        int col = 16 * t + cc;
        bool ok = kp < 32;
        sSB[i] = ok ? pack2(sub_w[(2 * kp) * 64 + col], sub_w[(2 * kp + 1) * 64 + col]) : 0u;
        sCX[i] = ok ? pack2(ctx_w[(2 * kp) * 64 + col], ctx_w[(2 * kp + 1) * 64 + col]) : 0u;
    }
    __syncthreads();

    int w = tid >> 6;
    int lane = tid & 63;
    int q = lane >> 4;
    int c = lane & 15;
    int base = (blockIdx.x * 4 + w) * 16;

    const uint4* hrow = (const uint4*)(h2u + (size_t)(base + c) * 40);
    FragU a0, a1, a2;
    a0.u = hrow[q];
    a1.u = hrow[4 + q];
    a2.u = make_uint4(0u, 0u, 0u, 0u);
    if (q < 2) a2.u = hrow[8 + q];

    f32x4 acc[4];
    #pragma unroll
    for (int t = 0; t < 4; t++) {
        const unsigned* pb = sOE + (t * 16 + c) * 48 + 4 * q;
        FragU b0, b1, b2;
        b0.u = *(const uint4*)(pb);
        b1.u = *(const uint4*)(pb + 16);
        b2.u = *(const uint4*)(pb + 32);
        f32x4 z = {0.f, 0.f, 0.f, 0.f};
        acc[t] = __builtin_amdgcn_mfma_f32_16x16x32_bf16(a0.b, b0.b, z, 0, 0, 0);
        acc[t] = __builtin_amdgcn_mfma_f32_16x16x32_bf16(a1.b, b1.b, acc[t], 0, 0, 0);
        acc[t] = __builtin_amdgcn_mfma_f32_16x16x32_bf16(a2.b, b2.b, acc[t], 0, 0, 0);
    }

    int mm[4], hn[4];
    #pragma unroll
    for (int r = 0; r < 4; r++) {
        int node = base + 4 * q + r;
        mm[r] = mapper[node];
        hn[r] = hop[node] + 1;
    }
    int sgA = base / S_;
    int k0 = (sgA + 1) * S_ - base;
    if (k0 > 16) k0 = 16;

    #pragma unroll
    for (int t = 0; t < 4; t++) {
        int col = 16 * t + c;
        float ob = oe_b[col];
        #pragma unroll
        for (int r = 0; r < 4; r++) {
            int row = 4 * q + r;
            float v = acc[t][r] + ob;
            sT[w][row * 68 + col] = v;
            int sg = (row < k0) ? sgA : sgA + 1;
            if (mm[r] == sg) {
                cent[(size_t)sg * 64 + col] = v * gall[hn[r] * 64 + col];
            }
        }
    }

    const float* trp = &sT[w][c * 68 + 8 * q];
    float4 v0 = *(const float4*)(trp);
    float4 v1 = *(const float4*)(trp + 4);
    float4 v2 = *(const float4*)(trp + 32);
    float4 v3 = *(const float4*)(trp + 36);
    FragU ap0, ap1;
    ap0.u = make_uint4(pack2(v0.x, v0.y), pack2(v0.z, v0.w), pack2(v1.x, v1.y), pack2(v1.z, v1.w));
    ap1.u = make_uint4(pack2(v2.x, v2.y), pack2(v2.z, v2.w), pack2(v3.x, v3.y), pack2(v3.z, v3.w));

    f32x4 sa[4], ca[4];
    #pragma unroll
    for (int t = 0; t < 4; t++) {
        const unsigned* ps = sSB + (t * 16 + c) * 40 + 4 * q;
        const unsigned* pc = sCX + (t * 16 + c) * 40 + 4 * q;
        FragU b0, b1, d0, d1;
        b0.u = *(const uint4*)(ps);
        b1.u = *(const uint4*)(ps + 16);
        d0.u = *(const uint4*)(pc);
        d1.u = *(const uint4*)(pc + 16);
        f32x4 z = {0.f, 0.f, 0.f, 0.f};
        sa[t] = __builtin_amdgcn_mfma_f32_16x16x32_bf16(ap0.b, b0.b, z, 0, 0, 0);
        sa[t] = __builtin_amdgcn_mfma_f32_16x16x32_bf16(ap1.b, b1.b, sa[t], 0, 0, 0);
        ca[t] = __builtin_amdgcn_mfma_f32_16x16x32_bf16(ap0.b, d0.b, z, 0, 0, 0);
        ca[t] = __builtin_amdgcn_mfma_f32_16x16x32_bf16(ap1.b, d1.b, ca[t], 0, 0, 0);
    }

    #pragma unroll
    for (int t = 0; t < 4; t++) {
        int col = 16 * t + c;
        float sb = sub_b[col], sgm = sub_g[col], sbt = sub_bt[col];
        float cb = ctx_b[col], cgm = ctx_g[col], cbt = ctx_bt[col];
        float sA = 0.f, sB = 0.f;
        #pragma unroll
        for (int r = 0; r < 4; r++) {
            int row = 4 * q + r;
            float sval = fmaxf(sgm * (sa[t][r] + sb) + sbt, 0.f) * gall[(20 + hn[r]) * 64 + col];
            float cval = fmaxf(cgm * (ca[t][r] + cb) + cbt, 0.f) * gall[(40 + hn[r]) * 64 + col];
            float partner = __shfl_xor(cval, 1);
            if ((c & 1) == 0) {
                ctxv[(size_t)(base + row) * 32 + (col >> 1)] = pack2(cval, partner);
            }
            if (row < k0) sA += sval; else sB += sval;
        }
        sA += __shfl_xor(sA, 16); sA += __shfl_xor(sA, 32);
        sB += __shfl_xor(sB, 16); sB += __shfl_xor(sB, 32);
        if (q == 0) {
            atomicAdd(&subp[(size_t)sgA * 64 + col], sA);
            if (k0 < 16) atomicAdd(&subp[(size_t)(sgA + 1) * 64 + col], sB);
        }
    }
}

// ---------------- ctx pool: gather ctxv rows by node-CSR (4-batched) ----------------
__global__ __launch_bounds__(256) void k_ctxpool(
    const unsigned* __restrict__ ctxv, const int* __restrict__ nstart,
    const int* __restrict__ nidx, float* __restrict__ ctxp)
{
    int w = threadIdx.x >> 6, d = threadIdx.x & 63;
    int n = blockIdx.x * 4 + w;
    if (n >= N_) return;
    int s0 = nstart[n], s1 = nstart[n + 1];
    int dh = d >> 1;
    float acc = 0.f;
    int i = s0;
    for (; i + 4 <= s1; i += 4) {
        int r0 = nidx[i], r1 = nidx[i + 1], r2 = nidx[i + 2], r3 = nidx[i + 3];
        float2 f0 = bf2f(ctxv[(size_t)r0 * 32 + dh]);
        float2 f1 = bf2f(ctxv[(size_t)r1 * 32 + dh]);
        float2 f2 = bf2f(ctxv[(size_t)r2 * 32 + dh]);
        float2 f3 = bf2f(ctxv[(size_t)r3 * 32 + dh]);
        acc += (d & 1) ? (f0.y + f1.y + f2.y + f3.y) : (f0.x + f1.x + f2.x + f3.x);
    }
    for (; i < s1; i++) {
        float2 f = bf2f(ctxv[(size_t)nidx[i] * 32 + dh]);
        acc += (d & 1) ? f.y : f.x;
    }
    ctxp[(size_t)n * 64 + d] = acc;
}

// ---------------- final: combine pools + out_encoder ----------------
__global__ __launch_bounds__(256) void k_final(
    const float* __restrict__ cent, const float* __restrict__ subp, const float* __restrict__ ctxp,
    const int* __restrict__ nstart,
    const float* __restrict__ fo_w, const float* __restrict__ fo_b,
    const float* __restrict__ fo_g, const float* __restrict__ fo_bt,
    float* __restrict__ out)
{
    __shared__ float sW[64 * 64];
    int tid = threadIdx.x;
    for (int i = tid; i < 4096; i += 256) sW[i] = fo_w[i];
    int d = tid & 63, grp = tid >> 6;
    float rb = fo_b[d], rg = fo_g[d], rbt = fo_bt[d];
    __syncthreads();
    for (int n = blockIdx.x * 4 + grp; n < N_; n += gridDim.x * 4) {
        float cm = (float)max(nstart[n + 1] - nstart[n], 1);
        size_t o = (size_t)n * 64 + d;
        float r = cent[o] + subp[o] * (1.f / 20.f) + ctxp[o] / cm;
        float dot = rb;
        #pragma unroll 8
        for (int k = 0; k < 64; k++) dot += __shfl(r, k) * sW[k * 64 + d];
        out[o] = rg * dot + rbt;
    }
}

// ---------------- launch ----------------
extern "C" void kernel_launch(void* const* d_in, const int* in_sizes, int n_in,
                              void* d_out, int out_size, void* d_ws, size_t ws_size,
                              hipStream_t stream) {
    const float* x         = (const float*)d_in[0];
    const float* edge_attr = (const float*)d_in[1];
    const float* hop_table = (const float*)d_in[2];
    const float* conv_w1   = (const float*)d_in[3];
    const float* bn1_g     = (const float*)d_in[4];
    const float* bn1_b     = (const float*)d_in[5];
    const float* conv_w2   = (const float*)d_in[6];
    const float* bn2_g     = (const float*)d_in[7];
    const float* bn2_b     = (const float*)d_in[8];
    const float* oe_w      = (const float*)d_in[9];
    const float* oe_b      = (const float*)d_in[10];
    const float* sub_w     = (const float*)d_in[11];
    const float* sub_b     = (const float*)d_in[12];
    const float* sub_g     = (const float*)d_in[13];
    const float* sub_bt    = (const float*)d_in[14];
    const float* ctx_w     = (const float*)d_in[15];
    const float* ctx_b     = (const float*)d_in[16];
    const float* ctx_g     = (const float*)d_in[17];
    const float* ctx_bt    = (const float*)d_in[18];
    const float* gc_w      = (const float*)d_in[19];
    const float* gc_b      = (const float*)d_in[20];
    const float* gs_w      = (const float*)d_in[21];
    const float* gs_b      = (const float*)d_in[22];
    const float* gx_w      = (const float*)d_in[23];
    const float* gx_b      = (const float*)d_in[24];
    const float* fo_w      = (const float*)d_in[25];
    const float* fo_b      = (const float*)d_in[26];
    const float* fo_g      = (const float*)d_in[27];
    const float* fo_bt     = (const float*)d_in[28];
    const int* nodes_mapper  = (const int*)d_in[29];
    const int* edges_mapper  = (const int*)d_in[30];
    const int* edge_index    = (const int*)d_in[31];
    const int* batch         = (const int*)d_in[32];
    const int* hop_indicator = (const int*)d_in[33];
    (void)batch;
    float* out = (float*)d_out;

    size_t off = 0;
    auto alloc = [&](size_t bytes) -> char* {
        char* p = (char*)d_ws + off;
        off = (off + bytes + 255) & ~(size_t)255;
        return p;
    };
    unsigned* hbuf0 = (unsigned*)alloc((size_t)NC_ * 40 * 4);  // 64 MB: h2
    unsigned* hbuf1 = (unsigned*)alloc((size_t)NC_ * 40 * 4);  // 64 MB: h1 -> ctxv
    int*   start    = (int*)alloc((size_t)(NC_ + 1) * 4);
    int*   cursor   = (int*)alloc((size_t)NC_ * 4);
    int*   bsums    = (int*)alloc(2048 * 4);
    int2*  e2       = (int2*)alloc((size_t)EC_ * 8);           // 16 MB
    float* cent     = (float*)alloc((size_t)N_ * 64 * 4);
    float* subp     = (float*)alloc((size_t)N_ * 64 * 4);
    float* ctxp     = (float*)alloc((size_t)N_ * 64 * 4);
    int*   nstart   = (int*)alloc((size_t)(N_ + 1) * 4);
    int*   cursor_n = (int*)alloc((size_t)N_ * 4);
    int*   bsums_n  = (int*)alloc(256 * 4);
    int*   nidx     = (int*)alloc((size_t)NC_ * 4);
    float* gall     = (float*)alloc((size_t)60 * 64 * 4);
    unsigned* xb    = (unsigned*)alloc((size_t)N_ * 32 * 4);   // 2.56 MB
    unsigned* htb   = (unsigned*)alloc((size_t)20 * 8 * 4);
    size_t ea16_bytes = (size_t)EB_ * 40 * 4;                  // 32 MB
    bool use_ea16 = (off + ea16_bytes + 256) <= ws_size;
    unsigned* eab = use_ea16 ? (unsigned*)alloc(ea16_bytes) : nullptr;
    unsigned* ctxv = hbuf1;
    (void)in_sizes; (void)n_in; (void)out_size;

    hipMemsetAsync(cursor, 0, (size_t)NC_ * 4, stream);
    hipMemsetAsync(cursor_n, 0, (size_t)N_ * 4, stream);
    hipMemsetAsync(subp, 0, (size_t)N_ * 64 * 4, stream);

    // tables
    k_xb16<<<(N_ * 32 + 255) / 256, 256, 0, stream>>>(xb, x);
    k_htb16<<<1, 160, 0, stream>>>(htb, hop_table);
    k_gates<<<20, 64, 0, stream>>>(hop_table, gc_w, gc_b, gs_w, gs_b, gx_w, gx_b, gall);
    if (use_ea16)
        k_ea16<<<(EB_ * 40 + 255) / 256, 256, 0, stream>>>(eab, edge_attr);

    // edge CSR (packed {src, emap*32+hop+1})
    k_degree<<<(EC_ + 255) / 256, 256, 0, stream>>>(edge_index, cursor);
    k_bsum<<<NB_, 256, 0, stream>>>(cursor, bsums, NC_);
    k_scan_bsums<<<1, 256, 0, stream>>>(bsums, NB_);
    k_scan_apply<<<NB_, 256, 0, stream>>>(cursor, start, bsums, NC_, EC_);
    k_fill<<<(EC_ + 255) / 256, 256, 0, stream>>>(edge_index, edges_mapper, hop_indicator,
                                                  cursor, e2);

    // node CSR (counting sort by nodes_mapper)
    k_hist<<<(NC_ + 255) / 256, 256, 0, stream>>>(nodes_mapper, cursor_n);
    k_bsum<<<NBN_, 256, 0, stream>>>(cursor_n, bsums_n, N_);
    k_scan_bsums<<<1, 256, 0, stream>>>(bsums_n, NBN_);
    k_scan_apply<<<NBN_, 256, 0, stream>>>(cursor_n, nstart, bsums_n, N_, NC_);
    k_fill_nodes<<<(NC_ + 255) / 256, 256, 0, stream>>>(nodes_mapper, cursor_n, nidx);

    // fused layers
    if (use_ea16) {
        k_gine_f<1, true><<<NC_ / 64, 256, 0, stream>>>(nullptr, xb, htb, nodes_mapper,
                                                        hop_indicator, eab, edge_attr,
                                                        start, e2, hbuf1, conv_w1, bn1_g, bn1_b);
        k_gine_f<2, true><<<NC_ / 64, 256, 0, stream>>>(hbuf1, xb, htb, nodes_mapper,
                                                        hop_indicator, eab, edge_attr,
                                                        start, e2, hbuf0, conv_w2, bn2_g, bn2_b);
    } else {
        k_gine_f<1, false><<<NC_ / 64, 256, 0, stream>>>(nullptr, xb, htb, nodes_mapper,
                                                         hop_indicator, eab, edge_attr,
                                                         start, e2, hbuf1, conv_w1, bn1_g, bn1_b);
        k_gine_f<2, false><<<NC_ / 64, 256, 0, stream>>>(hbuf1, xb, htb, nodes_mapper,
                                                         hop_indicator, eab, edge_attr,
                                                         start, e2, hbuf0, conv_w2, bn2_g, bn2_b);
    }

    // MFMA head (h2 = hbuf0; ctxv aliases hbuf1)
    k_headm<<<NC_ / 64, 256, 0, stream>>>(hbuf0, hop_indicator, nodes_mapper, gall,
                                          oe_w, oe_b, sub_w, sub_b, sub_g, sub_bt,
                                          ctx_w, ctx_b, ctx_g, ctx_bt,
                                          cent, subp, ctxv);

    // ctx pool via node-CSR gather
    k_ctxpool<<<N_ / 4, 256, 0, stream>>>(ctxv, nstart, nidx, ctxp);

    // final combine + out encoder
    k_final<<<1280, 256, 0, stream>>>(cent, subp, ctxp, nstart, fo_w, fo_b, fo_g, fo_bt, out);
}